// Round 2
// baseline (38621.786 us; speedup 1.0000x reference)
//
#include <hip/hip_runtime.h>
#include <math.h>

#define BB 2
#define CC 32
#define HH 64
#define WW 96
#define HWW (HH*WW)      // 6144
#define HID 128
#define ND 49
#define NBATCH (BB*ND)   // 98
#define CHUNK 7
#define NCHUNKS (NBATCH/CHUNK) // 14

// ---- workspace layout (float offsets) ----
#define OF_F2W   0L            // 393216
#define OF_CS    393216L       // 12288
#define OF_CVOL  405504L       // 602112  (persists into phase B)
#define OF_X1    1007616L      // 4128768 (phase A chunk scratch)
#define OF_X2    5136384L      // 1376256
#define OF_X3    6512640L      // 1376256
#define OF_X4    7888896L      // 688128
#define OF_X5    8577024L      // 1376256
// phase B (reuses phase-A chunk region; cvol still live)
#define OF_MEIN  1007616L      // 1019904
#define OF_M1    2027520L      // 1572864
#define OF_M2    3600384L      // 1572864
#define OF_M3    5173248L      // 1155072
#define OF_HX    6328320L      // 2752512
#define OF_HX2   9080832L      // 2752512
#define OF_Z     11833344L     // 1572864
#define OF_H1    13406208L     // 1572864
#define OF_S1    14979072L     // 3145728
// end: 18124800 floats = 72.5 MB

__device__ __forceinline__ float sigmoidf_(float x) { return 1.f / (1.f + expf(-x)); }
__device__ __forceinline__ float lrelu_(float x) { return x >= 0.f ? x : 0.01f * x; }

// -------- bilinear backward warp of fmap2 by flow; also channel-sum for validity --------
__global__ __launch_bounds__(256) void k_warp(const float* __restrict__ fmap2,
                                              const float* __restrict__ flow,
                                              float* __restrict__ f2w, float* __restrict__ cs)
{
    int idx = blockIdx.x * blockDim.x + threadIdx.x;
    if (idx >= BB * HWW) return;
    int b = idx / HWW, p = idx % HWW;
    int y = p / WW, x = p % WW;
    float u = flow[(b * 2 + 0) * HWW + p];
    float v = flow[(b * 2 + 1) * HWW + p];
    float fx = (float)x + u;
    float fy = (float)y + v;
    float fx0 = floorf(fx), fy0 = floorf(fy);
    float wx = fx - fx0, wy = fy - fy0;
    int x0 = (int)fx0, y0 = (int)fy0;
    int x1 = x0 + 1, y1 = y0 + 1;
    bool vx0 = (x0 >= 0) && (x0 < WW), vx1 = (x1 >= 0) && (x1 < WW);
    bool vy0 = (y0 >= 0) && (y0 < HH), vy1 = (y1 >= 0) && (y1 < HH);
    float m00 = (vy0 && vx0) ? (1.f - wy) * (1.f - wx) : 0.f;
    float m01 = (vy0 && vx1) ? (1.f - wy) * wx : 0.f;
    float m10 = (vy1 && vx0) ? wy * (1.f - wx) : 0.f;
    float m11 = (vy1 && vx1) ? wy * wx : 0.f;
    int cx0 = min(max(x0, 0), WW - 1), cx1 = min(max(x1, 0), WW - 1);
    int cy0 = min(max(y0, 0), HH - 1), cy1 = min(max(y1, 0), HH - 1);
    const float* fb = fmap2 + (long)b * CC * HWW;
    float s = 0.f;
    for (int c = 0; c < CC; ++c) {
        const float* fc = fb + (long)c * HWW;
        float g = m00 * fc[cy0 * WW + cx0] + m01 * fc[cy0 * WW + cx1]
                + m10 * fc[cy1 * WW + cx0] + m11 * fc[cy1 * WW + cx1];
        f2w[((long)(b * CC + c)) * HWW + p] = g;
        s += g;
    }
    cs[idx] = s;
}

// -------- matching-net conv1: fused mvol construction (virtual concat + validity) --------
__global__ __launch_bounds__(256) void k_conv1(const float* __restrict__ fmap1,
                                               const float* __restrict__ f2w,
                                               const float* __restrict__ cs,
                                               const float* __restrict__ w,
                                               const float* __restrict__ bias,
                                               float* __restrict__ out, int n0)
{
    int idx = blockIdx.x * blockDim.x + threadIdx.x;
    const int total = CHUNK * 96 * HH * WW;
    if (idx >= total) return;
    int x = idx % WW; int t = idx / WW;
    int y = t % HH; t /= HH;
    int o = t % 96; t /= 96;
    int n = n0 + t;
    int b = n / ND, k = n % ND;
    int di = k / 7 - 3;   // x shift
    int dj = k % 7 - 3;   // y shift
    float acc = bias[o];
    const float* wb = w + o * 64 * 9;
    #pragma unroll
    for (int ky = 0; ky < 3; ++ky) {
        int yy = y + ky - 1;
        if (yy < 0 || yy >= HH) continue;
        int ys = yy + dj;
        bool rowIn = (ys >= 0) && (ys < HH);
        #pragma unroll
        for (int kx = 0; kx < 3; ++kx) {
            int xx = x + kx - 1;
            if (xx < 0 || xx >= WW) continue;
            int xs = xx + di;
            bool in2 = rowIn && (xs >= 0) && (xs < WW);
            if (!in2) continue;
            if (cs[b * HWW + ys * WW + xs] == 0.f) continue;
            const float* f1p = fmap1 + ((long)(b * CC) * HH + yy) * WW + xx;
            const float* f2p = f2w + ((long)(b * CC) * HH + ys) * WW + xs;
            const float* wp = wb + ky * 3 + kx;
            for (int c = 0; c < CC; ++c) {
                acc = fmaf(wp[c * 9], f1p[(long)c * HWW], acc);
                acc = fmaf(wp[(c + 32) * 9], f2p[(long)c * HWW], acc);
            }
        }
    }
    out[idx] = fmaxf(acc, 0.f);
}

// -------- generic 3x3 conv, pad 1, runtime stride; ACT: 0 none, 1 relu, 2 lrelu --------
template<int ACT>
__global__ __launch_bounds__(256) void k_conv3x3(const float* __restrict__ in,
                                                 const float* __restrict__ w,
                                                 const float* __restrict__ bias,
                                                 float* __restrict__ out,
                                                 int N, int IC, int OC,
                                                 int IH, int IW, int OH, int OW, int stride)
{
    int idx = blockIdx.x * blockDim.x + threadIdx.x;
    long total = (long)N * OC * OH * OW;
    if (idx >= total) return;
    int x = idx % OW; long t = idx / OW;
    int y = (int)(t % OH); t /= OH;
    int o = (int)(t % OC); int n = (int)(t / OC);
    float acc = bias[o];
    const float* wb = w + (long)o * IC * 9;
    const float* ib = in + (long)n * IC * IH * IW;
    const long ihw = (long)IH * IW;
    #pragma unroll
    for (int ky = 0; ky < 3; ++ky) {
        int iy = y * stride + ky - 1;
        if (iy < 0 || iy >= IH) continue;
        #pragma unroll
        for (int kx = 0; kx < 3; ++kx) {
            int ix = x * stride + kx - 1;
            if (ix < 0 || ix >= IW) continue;
            const float* ip = ib + (long)iy * IW + ix;
            const float* wp = wb + ky * 3 + kx;
            for (int c = 0; c < IC; ++c)
                acc = fmaf(wp[c * 9], ip[c * ihw], acc);
        }
    }
    if (ACT == 1) acc = fmaxf(acc, 0.f);
    else if (ACT == 2) acc = lrelu_(acc);
    out[idx] = acc;
}

// -------- ConvTranspose (k=4,s=2,p=1) as lhs-dilated conv: (N,64,32,48) -> (N,32,64,96), relu --------
__global__ __launch_bounds__(256) void k_deconv(const float* __restrict__ in,
                                                const float* __restrict__ w,
                                                const float* __restrict__ bias,
                                                float* __restrict__ out, int N)
{
    int idx = blockIdx.x * blockDim.x + threadIdx.x;
    long total = (long)N * 32 * HH * WW;
    if (idx >= total) return;
    int x = idx % WW; long t = idx / WW;
    int y = (int)(t % HH); t /= HH;
    int o = (int)(t % 32); int n = (int)(t / 32);
    float acc = bias[o];
    const float* ib = in + (long)n * 64 * 32 * 48;
    #pragma unroll
    for (int ky = 0; ky < 4; ++ky) {
        int ty = y + ky - 2;
        if (ty < 0 || (ty & 1) || (ty >> 1) >= 32) continue;
        int ti = ty >> 1;
        #pragma unroll
        for (int kx = 0; kx < 4; ++kx) {
            int sx = x + kx - 2;
            if (sx < 0 || (sx & 1) || (sx >> 1) >= 48) continue;
            int si = sx >> 1;
            const float* ip = ib + (long)ti * 48 + si;
            const float* wp = w + (long)o * 64 * 16 + ky * 4 + kx;
            for (int c = 0; c < 64; ++c)
                acc = fmaf(wp[c * 16], ip[(long)c * 32 * 48], acc);
        }
    }
    out[idx] = fmaxf(acc, 0.f);
}

// -------- DAP: 49x49 1x1 over displacement channels; writes me_in channels [0,49) --------
__global__ __launch_bounds__(256) void k_dap(const float* __restrict__ cvol,
                                             const float* __restrict__ dw,
                                             const float* __restrict__ db,
                                             float* __restrict__ me_in)
{
    int idx = blockIdx.x * blockDim.x + threadIdx.x;
    if (idx >= BB * ND * HWW) return;
    int p = idx % HWW; int t = idx / HWW;
    int o = t % ND; int b = t / ND;
    float acc = db[o];
    const float* cb = cvol + (long)b * ND * HWW + p;
    const float* wp = dw + o * ND;
    #pragma unroll 7
    for (int k = 0; k < ND; ++k)
        acc = fmaf(wp[k], cb[(long)k * HWW], acc);
    me_in[((long)(b * 83 + o)) * HWW + p] = acc;
}

// -------- me_in channels [49,83): fmap1 (32) + flow (2) --------
__global__ __launch_bounds__(256) void k_me_tail(const float* __restrict__ fmap1,
                                                 const float* __restrict__ flow,
                                                 float* __restrict__ me_in)
{
    int idx = blockIdx.x * blockDim.x + threadIdx.x;
    if (idx >= BB * 34 * HWW) return;
    int p = idx % HWW; int t = idx / HWW;
    int c = t % 34; int b = t / 34;
    float v = (c < 32) ? fmap1[((long)(b * CC + c)) * HWW + p]
                       : flow[((long)(b * 2 + (c - 32))) * HWW + p];
    me_in[((long)(b * 83 + 49 + c)) * HWW + p] = v;
}

// -------- write hx head: hx[b, 0..127] = src --------
__global__ __launch_bounds__(256) void k_set_head(float* __restrict__ hx, const float* __restrict__ src)
{
    int idx = blockIdx.x * blockDim.x + threadIdx.x;
    if (idx >= BB * HID * HWW) return;
    int p = idx % HWW; int t = idx / HWW;
    int c = t % HID; int b = t / HID;
    hx[((long)(b * 224 + c)) * HWW + p] = src[idx];
}

// -------- write xg tails (m3: 94ch + flow: 2ch) into hx and hx2 channels [128,224) --------
__global__ __launch_bounds__(256) void k_set_tails(float* __restrict__ hx, float* __restrict__ hx2,
                                                   const float* __restrict__ m3,
                                                   const float* __restrict__ flow)
{
    int idx = blockIdx.x * blockDim.x + threadIdx.x;
    if (idx >= BB * 96 * HWW) return;
    int p = idx % HWW; int t = idx / HWW;
    int c = t % 96; int b = t / 96;
    float v = (c < 94) ? m3[((long)(b * 94 + c)) * HWW + p]
                       : flow[((long)(b * 2 + (c - 94))) * HWW + p];
    long di = ((long)(b * 224 + 128 + c)) * HWW + p;
    hx[di] = v;
    hx2[di] = v;
}

// -------- GRU z & r convs (1x5 if VERT=0, 5x1 if VERT=1); writes z and hx2 head = r*hstate --------
template<int VERT>
__global__ __launch_bounds__(256) void k_gru_zr(const float* __restrict__ hx,
                                                const float* __restrict__ wz, const float* __restrict__ bz,
                                                const float* __restrict__ wr, const float* __restrict__ br,
                                                const float* __restrict__ hstate,
                                                float* __restrict__ z, float* __restrict__ hx2)
{
    int idx = blockIdx.x * blockDim.x + threadIdx.x;
    if (idx >= BB * HID * HWW) return;
    int x = idx % WW; int t = idx / WW;
    int y = t % HH; t /= HH;
    int o = t % HID; int b = t / HID;
    float az = bz[o], ar = br[o];
    const float* wzb = wz + (long)o * 224 * 5;
    const float* wrb = wr + (long)o * 224 * 5;
    const float* ib = hx + (long)b * 224 * HWW;
    #pragma unroll
    for (int k = 0; k < 5; ++k) {
        int iy = VERT ? (y + k - 2) : y;
        int ix = VERT ? x : (x + k - 2);
        if (iy < 0 || iy >= HH || ix < 0 || ix >= WW) continue;
        const float* ip = ib + (long)iy * WW + ix;
        for (int c = 0; c < 224; ++c) {
            float v = ip[(long)c * HWW];
            az = fmaf(wzb[c * 5 + k], v, az);
            ar = fmaf(wrb[c * 5 + k], v, ar);
        }
    }
    float zv = sigmoidf_(az);
    float rv = sigmoidf_(ar);
    z[idx] = zv;
    hx2[((long)(b * 224 + o)) * HWW + (y * WW + x)] = rv * hstate[idx];
}

// -------- GRU q conv + state update: hout = (1-z)*hstate + z*tanh(conv(hx2, wq)) --------
template<int VERT>
__global__ __launch_bounds__(256) void k_gru_q(const float* __restrict__ hx2,
                                               const float* __restrict__ wq, const float* __restrict__ bq,
                                               const float* __restrict__ z,
                                               const float* __restrict__ hstate,
                                               float* __restrict__ hout)
{
    int idx = blockIdx.x * blockDim.x + threadIdx.x;
    if (idx >= BB * HID * HWW) return;
    int x = idx % WW; int t = idx / WW;
    int y = t % HH; t /= HH;
    int o = t % HID; int b = t / HID;
    float aq = bq[o];
    const float* wqb = wq + (long)o * 224 * 5;
    const float* ib = hx2 + (long)b * 224 * HWW;
    #pragma unroll
    for (int k = 0; k < 5; ++k) {
        int iy = VERT ? (y + k - 2) : y;
        int ix = VERT ? x : (x + k - 2);
        if (iy < 0 || iy >= HH || ix < 0 || ix >= WW) continue;
        const float* ip = ib + (long)iy * WW + ix;
        for (int c = 0; c < 224; ++c)
            aq = fmaf(wqb[c * 5 + k], ip[(long)c * HWW], aq);
    }
    float q = tanhf(aq);
    float zv = z[idx];
    hout[idx] = (1.f - zv) * hstate[idx] + zv * q;
}

// -------- flow head layer 1: 1x1 128->256, lrelu --------
__global__ __launch_bounds__(256) void k_fh1(const float* __restrict__ h2,
                                             const float* __restrict__ w, const float* __restrict__ bias,
                                             float* __restrict__ s1)
{
    int idx = blockIdx.x * blockDim.x + threadIdx.x;
    if (idx >= BB * 256 * HWW) return;
    int p = idx % HWW; int t = idx / HWW;
    int o = t % 256; int b = t / 256;
    float acc = bias[o];
    const float* hb = h2 + (long)b * HID * HWW + p;
    const float* wp = w + (long)o * HID;
    for (int c = 0; c < HID; ++c)
        acc = fmaf(wp[c], hb[(long)c * HWW], acc);
    s1[idx] = lrelu_(acc);
}

// -------- flow head layer 2 + softmax + expectation + flow add (fused, 49 reg accumulators) --------
__global__ __launch_bounds__(256) void k_fh2(const float* __restrict__ s1,
                                             const float* __restrict__ w, const float* __restrict__ bias,
                                             const float* __restrict__ flow,
                                             float* __restrict__ outFlow)
{
    int idx = blockIdx.x * blockDim.x + threadIdx.x;
    if (idx >= BB * HWW) return;
    int p = idx % HWW; int b = idx / HWW;
    float lg[ND];
    #pragma unroll
    for (int k = 0; k < ND; ++k) lg[k] = bias[k];
    const float* sb = s1 + (long)b * 256 * HWW + p;
    for (int c = 0; c < 256; ++c) {
        float v = sb[(long)c * HWW];
        const float* wc = w + c;   // w[k*256 + c]
        #pragma unroll
        for (int k = 0; k < ND; ++k)
            lg[k] = fmaf(wc[k * 256], v, lg[k]);
    }
    float m = -1e30f;
    #pragma unroll
    for (int k = 0; k < ND; ++k) { lg[k] = lrelu_(lg[k]); m = fmaxf(m, lg[k]); }
    float s = 0.f, a0 = 0.f, a1 = 0.f;
    #pragma unroll
    for (int k = 0; k < ND; ++k) {
        float e = expf(lg[k] - m);
        s += e;
        a0 += e * (float)(k / 7 - 3);
        a1 += e * (float)(k % 7 - 3);
    }
    float inv = 1.f / s;
    outFlow[(long)(b * 2 + 0) * HWW + p] = flow[(long)(b * 2 + 0) * HWW + p] + a0 * inv;
    outFlow[(long)(b * 2 + 1) * HWW + p] = flow[(long)(b * 2 + 1) * HWW + p] + a1 * inv;
}

extern "C" void kernel_launch(void* const* d_in, const int* in_sizes, int n_in,
                              void* d_out, int out_size, void* d_ws, size_t ws_size,
                              hipStream_t stream)
{
    const float* fmap1 = (const float*)d_in[0];
    const float* fmap2 = (const float*)d_in[1];
    const float* h     = (const float*)d_in[2];
    const float* flow  = (const float*)d_in[3];
    // scalar 'i' sits at index 4 in setup_inputs() dict order; be robust either way
    int pb = (in_sizes[4] == 1) ? 5 : 4;
    const float* mn_w1 = (const float*)d_in[pb + 0];
    const float* mn_b1 = (const float*)d_in[pb + 1];
    const float* mn_w2 = (const float*)d_in[pb + 2];
    const float* mn_b2 = (const float*)d_in[pb + 3];
    const float* mn_w3 = (const float*)d_in[pb + 4];
    const float* mn_b3 = (const float*)d_in[pb + 5];
    const float* mn_w4 = (const float*)d_in[pb + 6];
    const float* mn_b4 = (const float*)d_in[pb + 7];
    const float* mn_wd = (const float*)d_in[pb + 8];
    const float* mn_bd = (const float*)d_in[pb + 9];
    const float* mn_w5 = (const float*)d_in[pb + 10];
    const float* mn_b5 = (const float*)d_in[pb + 11];
    const float* dap_w = (const float*)d_in[pb + 12];
    const float* dap_b = (const float*)d_in[pb + 13];
    const float* me_w1 = (const float*)d_in[pb + 14];
    const float* me_b1 = (const float*)d_in[pb + 15];
    const float* me_w2 = (const float*)d_in[pb + 16];
    const float* me_b2 = (const float*)d_in[pb + 17];
    const float* me_w3 = (const float*)d_in[pb + 18];
    const float* me_b3 = (const float*)d_in[pb + 19];
    const float* gz1_w = (const float*)d_in[pb + 20];
    const float* gz1_b = (const float*)d_in[pb + 21];
    const float* gr1_w = (const float*)d_in[pb + 22];
    const float* gr1_b = (const float*)d_in[pb + 23];
    const float* gq1_w = (const float*)d_in[pb + 24];
    const float* gq1_b = (const float*)d_in[pb + 25];
    const float* gz2_w = (const float*)d_in[pb + 26];
    const float* gz2_b = (const float*)d_in[pb + 27];
    const float* gr2_w = (const float*)d_in[pb + 28];
    const float* gr2_b = (const float*)d_in[pb + 29];
    const float* gq2_w = (const float*)d_in[pb + 30];
    const float* gq2_b = (const float*)d_in[pb + 31];
    const float* fh_w1 = (const float*)d_in[pb + 32];
    const float* fh_b1 = (const float*)d_in[pb + 33];
    const float* fh_w2 = (const float*)d_in[pb + 34];
    const float* fh_b2 = (const float*)d_in[pb + 35];

    float* ws = (float*)d_ws;
    float* f2w  = ws + OF_F2W;
    float* cs   = ws + OF_CS;
    float* cvol = ws + OF_CVOL;
    float* x1   = ws + OF_X1;
    float* x2   = ws + OF_X2;
    float* x3   = ws + OF_X3;
    float* x4   = ws + OF_X4;
    float* x5   = ws + OF_X5;
    float* mein = ws + OF_MEIN;
    float* m1   = ws + OF_M1;
    float* m2   = ws + OF_M2;
    float* m3   = ws + OF_M3;
    float* hx   = ws + OF_HX;
    float* hx2  = ws + OF_HX2;
    float* zb   = ws + OF_Z;
    float* h1   = ws + OF_H1;
    float* s1   = ws + OF_S1;

    float* outH = (float*)d_out;                   // (2,128,64,96)
    float* outFlow = outH + (long)BB * HID * HWW;  // (2,2,64,96)

    auto nb = [](long total) { return (unsigned)((total + 255) / 256); };

    // warp + channel-sum
    k_warp<<<nb(BB * HWW), 256, 0, stream>>>(fmap2, flow, f2w, cs);

    // matching net over 14 chunks of 7 displac-batches
    for (int ch = 0; ch < NCHUNKS; ++ch) {
        int n0 = ch * CHUNK;
        k_conv1<<<nb((long)CHUNK * 96 * HWW), 256, 0, stream>>>(fmap1, f2w, cs, mn_w1, mn_b1, x1, n0);
        k_conv3x3<1><<<nb((long)CHUNK * 128 * 32 * 48), 256, 0, stream>>>(x1, mn_w2, mn_b2, x2,
                                                                          CHUNK, 96, 128, 64, 96, 32, 48, 2);
        k_conv3x3<1><<<nb((long)CHUNK * 128 * 32 * 48), 256, 0, stream>>>(x2, mn_w3, mn_b3, x3,
                                                                          CHUNK, 128, 128, 32, 48, 32, 48, 1);
        k_conv3x3<1><<<nb((long)CHUNK * 64 * 32 * 48), 256, 0, stream>>>(x3, mn_w4, mn_b4, x4,
                                                                         CHUNK, 128, 64, 32, 48, 32, 48, 1);
        k_deconv<<<nb((long)CHUNK * 32 * HWW), 256, 0, stream>>>(x4, mn_wd, mn_bd, x5, CHUNK);
        k_conv3x3<0><<<nb((long)CHUNK * 1 * HWW), 256, 0, stream>>>(x5, mn_w5, mn_b5, cvol + (long)n0 * HWW,
                                                                    CHUNK, 32, 1, 64, 96, 64, 96, 1);
    }

    // DAP + motion-encoder input assembly
    k_dap<<<nb((long)BB * ND * HWW), 256, 0, stream>>>(cvol, dap_w, dap_b, mein);
    k_me_tail<<<nb((long)BB * 34 * HWW), 256, 0, stream>>>(fmap1, flow, mein);

    // motion encoder
    k_conv3x3<2><<<nb((long)BB * 128 * HWW), 256, 0, stream>>>(mein, me_w1, me_b1, m1,
                                                               BB, 83, 128, 64, 96, 64, 96, 1);
    k_conv3x3<2><<<nb((long)BB * 128 * HWW), 256, 0, stream>>>(m1, me_w2, me_b2, m2,
                                                               BB, 128, 128, 64, 96, 64, 96, 1);
    k_conv3x3<0><<<nb((long)BB * 94 * HWW), 256, 0, stream>>>(m2, me_w3, me_b3, m3,
                                                              BB, 128, 94, 64, 96, 64, 96, 1);

    // GRU 1 (horizontal 1x5)
    k_set_head<<<nb((long)BB * HID * HWW), 256, 0, stream>>>(hx, h);
    k_set_tails<<<nb((long)BB * 96 * HWW), 256, 0, stream>>>(hx, hx2, m3, flow);
    k_gru_zr<0><<<nb((long)BB * HID * HWW), 256, 0, stream>>>(hx, gz1_w, gz1_b, gr1_w, gr1_b, h, zb, hx2);
    k_gru_q<0><<<nb((long)BB * HID * HWW), 256, 0, stream>>>(hx2, gq1_w, gq1_b, zb, h, h1);

    // GRU 2 (vertical 5x1)
    k_set_head<<<nb((long)BB * HID * HWW), 256, 0, stream>>>(hx, h1);
    k_gru_zr<1><<<nb((long)BB * HID * HWW), 256, 0, stream>>>(hx, gz2_w, gz2_b, gr2_w, gr2_b, h1, zb, hx2);
    k_gru_q<1><<<nb((long)BB * HID * HWW), 256, 0, stream>>>(hx2, gq2_w, gq2_b, zb, h1, outH);

    // flow head
    k_fh1<<<nb((long)BB * 256 * HWW), 256, 0, stream>>>(outH, fh_w1, fh_b1, s1);
    k_fh2<<<nb((long)BB * HWW), 256, 0, stream>>>(s1, fh_w2, fh_b2, flow, outFlow);
}

// Round 3
// 4102.562 us; speedup vs baseline: 9.4141x; 9.4141x over previous
//
#include <hip/hip_runtime.h>
#include <math.h>

#define BB 2
#define CC 32
#define HH 64
#define WW 96
#define HWW (HH*WW)      // 6144
#define HID 128
#define ND 49

__device__ __forceinline__ float sigmoidf_(float x) { return 1.f / (1.f + expf(-x)); }
__device__ __forceinline__ float lrelu_(float x) { return x >= 0.f ? x : 0.01f * x; }

// ---- weight transpose: w[(o*IC+c)*NT+t] -> wt[(t*IC+c)*OCp+o] ----
__global__ __launch_bounds__(256) void k_wt(const float* __restrict__ w, float* __restrict__ wt,
                                            int OC, int OCp, int IC, int NT)
{
    int i = blockIdx.x * 256 + threadIdx.x;
    if (i >= OC * IC * NT) return;
    int t = i % NT; int c = (i / NT) % IC; int o = i / (NT * IC);
    wt[((long)t * IC + c) * OCp + o] = w[i];
}

// ---- bilinear backward warp of fmap2 by flow; also channel-sum for validity ----
__global__ __launch_bounds__(256) void k_warp(const float* __restrict__ fmap2,
                                              const float* __restrict__ flow,
                                              float* __restrict__ f2w, float* __restrict__ cs)
{
    int idx = blockIdx.x * blockDim.x + threadIdx.x;
    if (idx >= BB * HWW) return;
    int b = idx / HWW, p = idx % HWW;
    int y = p / WW, x = p % WW;
    float u = flow[(b * 2 + 0) * HWW + p];
    float v = flow[(b * 2 + 1) * HWW + p];
    float fx = (float)x + u;
    float fy = (float)y + v;
    float fx0 = floorf(fx), fy0 = floorf(fy);
    float wx = fx - fx0, wy = fy - fy0;
    int x0 = (int)fx0, y0 = (int)fy0;
    int x1 = x0 + 1, y1 = y0 + 1;
    bool vx0 = (x0 >= 0) && (x0 < WW), vx1 = (x1 >= 0) && (x1 < WW);
    bool vy0 = (y0 >= 0) && (y0 < HH), vy1 = (y1 >= 0) && (y1 < HH);
    float m00 = (vy0 && vx0) ? (1.f - wy) * (1.f - wx) : 0.f;
    float m01 = (vy0 && vx1) ? (1.f - wy) * wx : 0.f;
    float m10 = (vy1 && vx0) ? wy * (1.f - wx) : 0.f;
    float m11 = (vy1 && vx1) ? wy * wx : 0.f;
    int cx0 = min(max(x0, 0), WW - 1), cx1 = min(max(x1, 0), WW - 1);
    int cy0 = min(max(y0, 0), HH - 1), cy1 = min(max(y1, 0), HH - 1);
    const float* fb = fmap2 + (long)b * CC * HWW;
    float s = 0.f;
    for (int c = 0; c < CC; ++c) {
        const float* fc = fb + (long)c * HWW;
        float g = m00 * fc[cy0 * WW + cx0] + m01 * fc[cy0 * WW + cx1]
                + m10 * fc[cy1 * WW + cx0] + m11 * fc[cy1 * WW + cx1];
        f2w[((long)(b * CC + c)) * HWW + p] = g;
        s += g;
    }
    cs[idx] = s;
}

// ---- matching-net conv1 fused with mvol construction; TOC output chans per thread ----
template<int TOC>
__global__ __launch_bounds__(256) void k_conv1t(const float* __restrict__ fmap1,
                                                const float* __restrict__ f2w,
                                                const float* __restrict__ cs,
                                                const float* __restrict__ wt,
                                                const float* __restrict__ bias,
                                                float* __restrict__ out, int n0, int N)
{
    int pix = blockIdx.x * 256 + threadIdx.x;
    if (pix >= N * HWW) return;
    int nl = pix / HWW, p = pix % HWW;
    int y = p / WW, x = p % WW;
    int n = n0 + nl;
    int b = n / ND, k = n % ND;
    int di = k / 7 - 3, dj = k % 7 - 3;
    int o0 = blockIdx.y * TOC;
    const float* f1b = fmap1 + (long)b * CC * HWW;
    const float* f2b = f2w + (long)b * CC * HWW;
    const float* csb = cs + b * HWW;
    int offA[9], offB[9];
    float msk[9];
    #pragma unroll
    for (int t = 0; t < 9; ++t) {
        int yy = y + t / 3 - 1, xx = x + t % 3 - 1;
        int ys = yy + dj, xs = xx + di;
        bool v = yy >= 0 && yy < HH && xx >= 0 && xx < WW && ys >= 0 && ys < HH && xs >= 0 && xs < WW;
        int oa = v ? yy * WW + xx : 0;
        int ob = v ? ys * WW + xs : 0;
        v = v && (csb[ob] != 0.f);
        offA[t] = oa; offB[t] = ob; msk[t] = v ? 1.f : 0.f;
    }
    float acc[TOC];
    #pragma unroll
    for (int j = 0; j < TOC; ++j) acc[j] = bias[o0 + j];
    for (int c = 0; c < CC; ++c) {
        const float* f1c = f1b + (long)c * HWW;
        const float* f2c = f2b + (long)c * HWW;
        float a1[9], a2[9];
        #pragma unroll
        for (int t = 0; t < 9; ++t) { a1[t] = msk[t] * f1c[offA[t]]; a2[t] = msk[t] * f2c[offB[t]]; }
        #pragma unroll
        for (int t = 0; t < 9; ++t) {
            const float* wA = wt + ((long)t * 64 + c) * 96 + o0;
            const float* wB = wt + ((long)t * 64 + 32 + c) * 96 + o0;
            #pragma unroll
            for (int j = 0; j < TOC; ++j)
                acc[j] = fmaf(wA[j], a1[t], fmaf(wB[j], a2[t], acc[j]));
        }
    }
    float* ob = out + ((long)nl * 96 + o0) * HWW + p;
    #pragma unroll
    for (int j = 0; j < TOC; ++j) ob[(long)j * HWW] = fmaxf(acc[j], 0.f);
}

// ---- generic register-tiled conv; weights pre-transposed [t][c][o] ----
template<int KH, int KW, int PH, int PW, int ST, int TOC, int ACT>
__global__ __launch_bounds__(256) void k_convg(const float* __restrict__ in,
                                               const float* __restrict__ wt,
                                               const float* __restrict__ bias,
                                               float* __restrict__ out,
                                               int N, int IC, int OC, int OCp,
                                               int IH, int IW, int OH, int OW)
{
    constexpr int NT = KH * KW;
    int pix = blockIdx.x * 256 + threadIdx.x;
    if (pix >= N * OH * OW) return;
    int n = pix / (OH * OW), rem = pix % (OH * OW);
    int y = rem / OW, x = rem % OW;
    int o0 = blockIdx.y * TOC;
    const long IHW = (long)IH * IW;
    const float* ib = in + (long)n * IC * IHW;
    int off[NT]; float msk[NT];
    #pragma unroll
    for (int t = 0; t < NT; ++t) {
        int iy = y * ST + t / KW - PH, ix = x * ST + t % KW - PW;
        bool v = iy >= 0 && iy < IH && ix >= 0 && ix < IW;
        off[t] = v ? iy * IW + ix : 0;
        msk[t] = v ? 1.f : 0.f;
    }
    float acc[TOC];
    #pragma unroll
    for (int j = 0; j < TOC; ++j) acc[j] = (o0 + j < OC) ? bias[o0 + j] : 0.f;
    for (int c = 0; c < IC; ++c) {
        const float* ic_ = ib + (long)c * IHW;
        float v[NT];
        #pragma unroll
        for (int t = 0; t < NT; ++t) v[t] = msk[t] * ic_[off[t]];
        #pragma unroll
        for (int t = 0; t < NT; ++t) {
            const float* wp = wt + ((long)t * IC + c) * OCp + o0;
            #pragma unroll
            for (int j = 0; j < TOC; ++j) acc[j] = fmaf(wp[j], v[t], acc[j]);
        }
    }
    float* ob = out + (long)n * OC * OH * OW + rem;
    #pragma unroll
    for (int j = 0; j < TOC; ++j) {
        if (o0 + j < OC) {
            float a = acc[j];
            if (ACT == 1) a = fmaxf(a, 0.f);
            else if (ACT == 2) a = lrelu_(a);
            ob[(long)(o0 + j) * OH * OW] = a;
        }
    }
}

// ---- deconv (k=4,s=2,p=1) as 2x2 output quads per thread (static tap parity) ----
template<int TOC>
__global__ __launch_bounds__(256) void k_deconvt(const float* __restrict__ in,
                                                 const float* __restrict__ wt,
                                                 const float* __restrict__ bias,
                                                 float* __restrict__ out, int N)
{
    int idx = blockIdx.x * 256 + threadIdx.x;
    if (idx >= N * 1536) return;     // 32x48 quads
    int n = idx / 1536, rem = idx % 1536;
    int Y = rem / 48, X = rem % 48;
    int o0 = blockIdx.y * TOC;
    const float* ib = in + (long)n * 64 * 1536;
    float acc[4][TOC];
    #pragma unroll
    for (int q = 0; q < 4; ++q)
        #pragma unroll
        for (int j = 0; j < TOC; ++j) acc[q][j] = bias[o0 + j];
    float mr[3], mc[3]; int ro[3], co[3];
    #pragma unroll
    for (int a = 0; a < 3; ++a) {
        int t = Y - 1 + a; bool v = (t >= 0 && t < 32);
        mr[a] = v ? 1.f : 0.f; ro[a] = v ? t : 0;
        int s = X - 1 + a; bool w = (s >= 0 && s < 48);
        mc[a] = w ? 1.f : 0.f; co[a] = w ? s : 0;
    }
    for (int c = 0; c < 64; ++c) {
        const float* ic_ = ib + (long)c * 1536;
        float v[3][3];
        #pragma unroll
        for (int a = 0; a < 3; ++a)
            #pragma unroll
            for (int b2 = 0; b2 < 3; ++b2)
                v[a][b2] = mr[a] * mc[b2] * ic_[ro[a] * 48 + co[b2]];
        #pragma unroll
        for (int ry = 0; ry < 2; ++ry)
            #pragma unroll
            for (int rx = 0; rx < 2; ++rx)
                #pragma unroll
                for (int a = 0; a < 2; ++a)
                    #pragma unroll
                    for (int b2 = 0; b2 < 2; ++b2) {
                        int tap = (ry + 2 * a) * 4 + (rx + 2 * b2);
                        const float* wp = wt + ((long)tap * 64 + c) * 32 + o0;
                        #pragma unroll
                        for (int j = 0; j < TOC; ++j)
                            acc[ry * 2 + rx][j] = fmaf(wp[j], v[ry + a][rx + b2], acc[ry * 2 + rx][j]);
                    }
    }
    #pragma unroll
    for (int ry = 0; ry < 2; ++ry)
        #pragma unroll
        for (int rx = 0; rx < 2; ++rx) {
            int oy = 2 * Y + ry, ox = 2 * X + rx;
            #pragma unroll
            for (int j = 0; j < TOC; ++j)
                out[((long)n * 32 + o0 + j) * HWW + oy * WW + ox] = fmaxf(acc[ry * 2 + rx][j], 0.f);
        }
}

// ---- conv5 (32->1, 3x3): 4 pixels per thread, float4 row loads ----
__global__ __launch_bounds__(256) void k_conv5v(const float* __restrict__ in,
                                                const float* __restrict__ w5,
                                                const float* __restrict__ b5,
                                                float* __restrict__ out, int N)
{
    int idx = blockIdx.x * 256 + threadIdx.x;
    if (idx >= N * 1536) return;     // 64 rows x 24 groups of 4
    int n = idx / 1536, rem = idx % 1536;
    int y = rem / 24, g = rem % 24;
    int x0 = g * 4;
    const float* ib = in + (long)n * 32 * HWW;
    float acc[4];
    float bb = b5[0];
    #pragma unroll
    for (int i = 0; i < 4; ++i) acc[i] = bb;
    float mrow[3]; int ry[3];
    #pragma unroll
    for (int a = 0; a < 3; ++a) { int t = y - 1 + a; bool v = (t >= 0 && t < HH); mrow[a] = v ? 1.f : 0.f; ry[a] = v ? t : 0; }
    bool hasL = (x0 > 0), hasR = (x0 + 4 < WW);
    for (int c = 0; c < 32; ++c) {
        const float* cp = ib + (long)c * HWW;
        const float* wr = w5 + c * 9;
        #pragma unroll
        for (int a = 0; a < 3; ++a) {
            const float* rp = cp + ry[a] * WW + x0;
            float4 v4 = *(const float4*)rp;
            float s[6];
            s[0] = (hasL ? rp[-1] : 0.f) * mrow[a];
            s[1] = v4.x * mrow[a]; s[2] = v4.y * mrow[a]; s[3] = v4.z * mrow[a]; s[4] = v4.w * mrow[a];
            s[5] = (hasR ? rp[4] : 0.f) * mrow[a];
            #pragma unroll
            for (int kx = 0; kx < 3; ++kx) {
                float wv = wr[a * 3 + kx];
                #pragma unroll
                for (int i = 0; i < 4; ++i)
                    acc[i] = fmaf(wv, s[i + kx], acc[i]);
            }
        }
    }
    float* op = out + (long)n * HWW + y * WW + x0;
    #pragma unroll
    for (int i = 0; i < 4; ++i) op[i] = acc[i];
}

// ---- DAP: 49 outputs per thread/pixel; dwt is [k][o] ----
__global__ __launch_bounds__(256) void k_dapt(const float* __restrict__ cvol,
                                              const float* __restrict__ dwt,
                                              const float* __restrict__ db,
                                              float* __restrict__ mein)
{
    int idx = blockIdx.x * 256 + threadIdx.x;
    if (idx >= BB * HWW) return;
    int b = idx / HWW, p = idx % HWW;
    float acc[ND];
    #pragma unroll
    for (int o = 0; o < ND; ++o) acc[o] = db[o];
    const float* cb = cvol + (long)b * ND * HWW + p;
    for (int k = 0; k < ND; ++k) {
        float v = cb[(long)k * HWW];
        const float* wp = dwt + k * ND;
        #pragma unroll
        for (int o = 0; o < ND; ++o) acc[o] = fmaf(wp[o], v, acc[o]);
    }
    float* ob = mein + (long)b * 83 * HWW + p;
    #pragma unroll
    for (int o = 0; o < ND; ++o) ob[(long)o * HWW] = acc[o];
}

// ---- me_in channels [49,83): fmap1 (32) + flow (2) ----
__global__ __launch_bounds__(256) void k_me_tail(const float* __restrict__ fmap1,
                                                 const float* __restrict__ flow,
                                                 float* __restrict__ me_in)
{
    int idx = blockIdx.x * blockDim.x + threadIdx.x;
    if (idx >= BB * 34 * HWW) return;
    int p = idx % HWW; int t = idx / HWW;
    int c = t % 34; int b = t / 34;
    float v = (c < 32) ? fmap1[((long)(b * CC + c)) * HWW + p]
                       : flow[((long)(b * 2 + (c - 32))) * HWW + p];
    me_in[((long)(b * 83 + 49 + c)) * HWW + p] = v;
}

// ---- hx head copy ----
__global__ __launch_bounds__(256) void k_set_head(float* __restrict__ hx, const float* __restrict__ src)
{
    int idx = blockIdx.x * blockDim.x + threadIdx.x;
    if (idx >= BB * HID * HWW) return;
    int p = idx % HWW; int t = idx / HWW;
    int c = t % HID; int b = t / HID;
    hx[((long)(b * 224 + c)) * HWW + p] = src[idx];
}

// ---- xg tails into hx and hx2 channels [128,224) ----
__global__ __launch_bounds__(256) void k_set_tails(float* __restrict__ hx, float* __restrict__ hx2,
                                                   const float* __restrict__ m3,
                                                   const float* __restrict__ flow)
{
    int idx = blockIdx.x * blockDim.x + threadIdx.x;
    if (idx >= BB * 96 * HWW) return;
    int p = idx % HWW; int t = idx / HWW;
    int c = t % 96; int b = t / 96;
    float v = (c < 94) ? m3[((long)(b * 94 + c)) * HWW + p]
                       : flow[((long)(b * 2 + (c - 94))) * HWW + p];
    long di = ((long)(b * 224 + 128 + c)) * HWW + p;
    hx[di] = v;
    hx2[di] = v;
}

// ---- GRU z & r convs fused, register-tiled; writes z and hx2 head = r*hstate ----
template<int VERT, int TOC>
__global__ __launch_bounds__(256) void k_gru_zrt(const float* __restrict__ hx,
                                                 const float* __restrict__ wtz, const float* __restrict__ bz,
                                                 const float* __restrict__ wtr, const float* __restrict__ br,
                                                 const float* __restrict__ hstate,
                                                 float* __restrict__ z, float* __restrict__ hx2)
{
    int pix = blockIdx.x * 256 + threadIdx.x;
    if (pix >= BB * HWW) return;
    int b = pix / HWW, p = pix % HWW;
    int y = p / WW, x = p % WW;
    int o0 = blockIdx.y * TOC;
    int off[5]; float msk[5];
    #pragma unroll
    for (int t = 0; t < 5; ++t) {
        int iy = VERT ? (y + t - 2) : y;
        int ix = VERT ? x : (x + t - 2);
        bool v = iy >= 0 && iy < HH && ix >= 0 && ix < WW;
        off[t] = v ? iy * WW + ix : 0;
        msk[t] = v ? 1.f : 0.f;
    }
    float accz[TOC], accr[TOC];
    #pragma unroll
    for (int j = 0; j < TOC; ++j) { accz[j] = bz[o0 + j]; accr[j] = br[o0 + j]; }
    const float* ib = hx + (long)b * 224 * HWW;
    for (int c = 0; c < 224; ++c) {
        const float* ic_ = ib + (long)c * HWW;
        float v[5];
        #pragma unroll
        for (int t = 0; t < 5; ++t) v[t] = msk[t] * ic_[off[t]];
        #pragma unroll
        for (int t = 0; t < 5; ++t) {
            const float* wpz = wtz + ((long)t * 224 + c) * 128 + o0;
            const float* wpr = wtr + ((long)t * 224 + c) * 128 + o0;
            #pragma unroll
            for (int j = 0; j < TOC; ++j) {
                accz[j] = fmaf(wpz[j], v[t], accz[j]);
                accr[j] = fmaf(wpr[j], v[t], accr[j]);
            }
        }
    }
    #pragma unroll
    for (int j = 0; j < TOC; ++j) {
        float zv = sigmoidf_(accz[j]);
        float rv = sigmoidf_(accr[j]);
        long oi = (long)(b * HID + o0 + j) * HWW + p;
        z[oi] = zv;
        hx2[((long)(b * 224 + o0 + j)) * HWW + p] = rv * hstate[oi];
    }
}

// ---- GRU q conv + state update ----
template<int VERT, int TOC>
__global__ __launch_bounds__(256) void k_gru_qt(const float* __restrict__ hx2,
                                                const float* __restrict__ wtq, const float* __restrict__ bq,
                                                const float* __restrict__ z,
                                                const float* __restrict__ hstate,
                                                float* __restrict__ hout)
{
    int pix = blockIdx.x * 256 + threadIdx.x;
    if (pix >= BB * HWW) return;
    int b = pix / HWW, p = pix % HWW;
    int y = p / WW, x = p % WW;
    int o0 = blockIdx.y * TOC;
    int off[5]; float msk[5];
    #pragma unroll
    for (int t = 0; t < 5; ++t) {
        int iy = VERT ? (y + t - 2) : y;
        int ix = VERT ? x : (x + t - 2);
        bool v = iy >= 0 && iy < HH && ix >= 0 && ix < WW;
        off[t] = v ? iy * WW + ix : 0;
        msk[t] = v ? 1.f : 0.f;
    }
    float acc[TOC];
    #pragma unroll
    for (int j = 0; j < TOC; ++j) acc[j] = bq[o0 + j];
    const float* ib = hx2 + (long)b * 224 * HWW;
    for (int c = 0; c < 224; ++c) {
        const float* ic_ = ib + (long)c * HWW;
        float v[5];
        #pragma unroll
        for (int t = 0; t < 5; ++t) v[t] = msk[t] * ic_[off[t]];
        #pragma unroll
        for (int t = 0; t < 5; ++t) {
            const float* wp = wtq + ((long)t * 224 + c) * 128 + o0;
            #pragma unroll
            for (int j = 0; j < TOC; ++j) acc[j] = fmaf(wp[j], v[t], acc[j]);
        }
    }
    #pragma unroll
    for (int j = 0; j < TOC; ++j) {
        long oi = (long)(b * HID + o0 + j) * HWW + p;
        float q = tanhf(acc[j]);
        float zv = z[oi];
        hout[oi] = (1.f - zv) * hstate[oi] + zv * q;
    }
}

// ---- flow head layer 2 + softmax + expectation + flow add ----
__global__ __launch_bounds__(256) void k_fh2(const float* __restrict__ s1,
                                             const float* __restrict__ w, const float* __restrict__ bias,
                                             const float* __restrict__ flow,
                                             float* __restrict__ outFlow)
{
    int idx = blockIdx.x * blockDim.x + threadIdx.x;
    if (idx >= BB * HWW) return;
    int p = idx % HWW; int b = idx / HWW;
    float lg[ND];
    #pragma unroll
    for (int k = 0; k < ND; ++k) lg[k] = bias[k];
    const float* sb = s1 + (long)b * 256 * HWW + p;
    for (int c = 0; c < 256; ++c) {
        float v = sb[(long)c * HWW];
        const float* wc = w + c;   // w[k*256 + c]
        #pragma unroll
        for (int k = 0; k < ND; ++k)
            lg[k] = fmaf(wc[k * 256], v, lg[k]);
    }
    float m = -1e30f;
    #pragma unroll
    for (int k = 0; k < ND; ++k) { lg[k] = lrelu_(lg[k]); m = fmaxf(m, lg[k]); }
    float s = 0.f, a0 = 0.f, a1 = 0.f;
    #pragma unroll
    for (int k = 0; k < ND; ++k) {
        float e = expf(lg[k] - m);
        s += e;
        a0 += e * (float)(k / 7 - 3);
        a1 += e * (float)(k % 7 - 3);
    }
    float inv = 1.f / s;
    outFlow[(long)(b * 2 + 0) * HWW + p] = flow[(long)(b * 2 + 0) * HWW + p] + a0 * inv;
    outFlow[(long)(b * 2 + 1) * HWW + p] = flow[(long)(b * 2 + 1) * HWW + p] + a1 * inv;
}

extern "C" void kernel_launch(void* const* d_in, const int* in_sizes, int n_in,
                              void* d_out, int out_size, void* d_ws, size_t ws_size,
                              hipStream_t stream)
{
    const float* fmap1 = (const float*)d_in[0];
    const float* fmap2 = (const float*)d_in[1];
    const float* h     = (const float*)d_in[2];
    const float* flow  = (const float*)d_in[3];
    int pb = (in_sizes[4] == 1) ? 5 : 4;
    const float* mn_w1 = (const float*)d_in[pb + 0];
    const float* mn_b1 = (const float*)d_in[pb + 1];
    const float* mn_w2 = (const float*)d_in[pb + 2];
    const float* mn_b2 = (const float*)d_in[pb + 3];
    const float* mn_w3 = (const float*)d_in[pb + 4];
    const float* mn_b3 = (const float*)d_in[pb + 5];
    const float* mn_w4 = (const float*)d_in[pb + 6];
    const float* mn_b4 = (const float*)d_in[pb + 7];
    const float* mn_wd = (const float*)d_in[pb + 8];
    const float* mn_bd = (const float*)d_in[pb + 9];
    const float* mn_w5 = (const float*)d_in[pb + 10];
    const float* mn_b5 = (const float*)d_in[pb + 11];
    const float* dap_w = (const float*)d_in[pb + 12];
    const float* dap_b = (const float*)d_in[pb + 13];
    const float* me_w1 = (const float*)d_in[pb + 14];
    const float* me_b1 = (const float*)d_in[pb + 15];
    const float* me_w2 = (const float*)d_in[pb + 16];
    const float* me_b2 = (const float*)d_in[pb + 17];
    const float* me_w3 = (const float*)d_in[pb + 18];
    const float* me_b3 = (const float*)d_in[pb + 19];
    const float* gz1_w = (const float*)d_in[pb + 20];
    const float* gz1_b = (const float*)d_in[pb + 21];
    const float* gr1_w = (const float*)d_in[pb + 22];
    const float* gr1_b = (const float*)d_in[pb + 23];
    const float* gq1_w = (const float*)d_in[pb + 24];
    const float* gq1_b = (const float*)d_in[pb + 25];
    const float* gz2_w = (const float*)d_in[pb + 26];
    const float* gz2_b = (const float*)d_in[pb + 27];
    const float* gr2_w = (const float*)d_in[pb + 28];
    const float* gr2_b = (const float*)d_in[pb + 29];
    const float* gq2_w = (const float*)d_in[pb + 30];
    const float* gq2_b = (const float*)d_in[pb + 31];
    const float* fh_w1 = (const float*)d_in[pb + 32];
    const float* fh_b1 = (const float*)d_in[pb + 33];
    const float* fh_w2 = (const float*)d_in[pb + 34];
    const float* fh_b2 = (const float*)d_in[pb + 35];

    // ---- workspace bump allocation (floats, 256-aligned) ----
    auto A256 = [](size_t n) { return (n + 255) & ~(size_t)255; };
    size_t base = 0;
    auto alloc = [&](size_t n) { size_t o = base; base += A256(n); return o; };
    size_t o_f2w  = alloc((size_t)BB * CC * HWW);
    size_t o_cs   = alloc((size_t)BB * HWW);
    size_t o_cvol = alloc((size_t)98 * HWW);
    size_t o_wt1  = alloc(9 * 64 * 96);
    size_t o_wt2  = alloc(9 * 96 * 128);
    size_t o_wt3  = alloc(9 * 128 * 128);
    size_t o_wt4  = alloc(9 * 128 * 64);
    size_t o_wtd  = alloc(16 * 64 * 32);
    size_t o_wme1 = alloc(9 * 83 * 128);
    size_t o_wme2 = alloc(9 * 128 * 128);
    size_t o_wme3 = alloc(9 * 128 * 96);   // OCp=96 padded
    size_t o_wgz1 = alloc(5 * 224 * 128);
    size_t o_wgr1 = alloc(5 * 224 * 128);
    size_t o_wgq1 = alloc(5 * 224 * 128);
    size_t o_wgz2 = alloc(5 * 224 * 128);
    size_t o_wgr2 = alloc(5 * 224 * 128);
    size_t o_wgq2 = alloc(5 * 224 * 128);
    size_t o_wfh1 = alloc(128 * 256);
    size_t o_wdap = alloc(49 * 49);
    size_t R0 = base;
    // phase-B buffers from R0
    size_t b2 = R0;
    auto allocB = [&](size_t n) { size_t o = b2; b2 += A256(n); return o; };
    size_t o_mein = allocB((size_t)BB * 83 * HWW);
    size_t o_m1   = allocB((size_t)BB * 128 * HWW);
    size_t o_m2   = allocB((size_t)BB * 128 * HWW);
    size_t o_m3   = allocB((size_t)BB * 94 * HWW);
    size_t o_hx   = allocB((size_t)BB * 224 * HWW);
    size_t o_hx2  = allocB((size_t)BB * 224 * HWW);
    size_t o_z    = allocB((size_t)BB * 128 * HWW);
    size_t o_h1   = allocB((size_t)BB * 128 * HWW);
    size_t Bsz = b2 - R0;
    size_t o_s1 = R0;  // overlays mein..m2 (4.1M >= 3.15M needed)

    // choose chunk size from available workspace
    auto Asz = [&](size_t c) {
        return A256(c * (size_t)96 * HWW) + A256(c * (size_t)128 * 1536) + A256(c * (size_t)128 * 1536)
             + A256(c * (size_t)64 * 1536) + A256(c * (size_t)32 * HWW);
    };
    size_t wsFloats = ws_size / 4;
    int CH = 7;
    {
        const int cand[3] = {98, 49, 14};
        for (int i = 0; i < 3; ++i) {
            size_t A = Asz((size_t)cand[i]);
            size_t need = R0 + (A > Bsz ? A : Bsz);
            if (need <= wsFloats) { CH = cand[i]; break; }
        }
    }
    size_t xo = R0;
    size_t o_x1 = xo; xo += A256((size_t)CH * 96 * HWW);
    size_t o_x2 = xo; xo += A256((size_t)CH * 128 * 1536);
    size_t o_x3 = xo; xo += A256((size_t)CH * 128 * 1536);
    size_t o_x4 = xo; xo += A256((size_t)CH * 64 * 1536);
    size_t o_x5 = xo;

    float* ws = (float*)d_ws;
    float* f2w  = ws + o_f2w;  float* cs   = ws + o_cs;   float* cvol = ws + o_cvol;
    float* wt1  = ws + o_wt1;  float* wt2  = ws + o_wt2;  float* wt3  = ws + o_wt3;
    float* wt4  = ws + o_wt4;  float* wtd  = ws + o_wtd;
    float* wme1 = ws + o_wme1; float* wme2 = ws + o_wme2; float* wme3 = ws + o_wme3;
    float* wgz1 = ws + o_wgz1; float* wgr1 = ws + o_wgr1; float* wgq1 = ws + o_wgq1;
    float* wgz2 = ws + o_wgz2; float* wgr2 = ws + o_wgr2; float* wgq2 = ws + o_wgq2;
    float* wfh1 = ws + o_wfh1; float* wdap = ws + o_wdap;
    float* x1 = ws + o_x1; float* x2 = ws + o_x2; float* x3 = ws + o_x3;
    float* x4 = ws + o_x4; float* x5 = ws + o_x5;
    float* mein = ws + o_mein; float* m1 = ws + o_m1; float* m2 = ws + o_m2; float* m3 = ws + o_m3;
    float* hx = ws + o_hx; float* hx2 = ws + o_hx2; float* zb = ws + o_z; float* h1 = ws + o_h1;
    float* s1 = ws + o_s1;

    float* outH = (float*)d_out;                   // (2,128,64,96)
    float* outFlow = outH + (long)BB * HID * HWW;  // (2,2,64,96)

    auto nb = [](long total) { return (unsigned)((total + 255) / 256); };

    // ---- weight transposes ----
    k_wt<<<nb(96L * 64 * 9), 256, 0, stream>>>(mn_w1, wt1, 96, 96, 64, 9);
    k_wt<<<nb(128L * 96 * 9), 256, 0, stream>>>(mn_w2, wt2, 128, 128, 96, 9);
    k_wt<<<nb(128L * 128 * 9), 256, 0, stream>>>(mn_w3, wt3, 128, 128, 128, 9);
    k_wt<<<nb(64L * 128 * 9), 256, 0, stream>>>(mn_w4, wt4, 64, 64, 128, 9);
    k_wt<<<nb(32L * 64 * 16), 256, 0, stream>>>(mn_wd, wtd, 32, 32, 64, 16);
    k_wt<<<nb(128L * 83 * 9), 256, 0, stream>>>(me_w1, wme1, 128, 128, 83, 9);
    k_wt<<<nb(128L * 128 * 9), 256, 0, stream>>>(me_w2, wme2, 128, 128, 128, 9);
    k_wt<<<nb(94L * 128 * 9), 256, 0, stream>>>(me_w3, wme3, 94, 96, 128, 9);
    k_wt<<<nb(128L * 224 * 5), 256, 0, stream>>>(gz1_w, wgz1, 128, 128, 224, 5);
    k_wt<<<nb(128L * 224 * 5), 256, 0, stream>>>(gr1_w, wgr1, 128, 128, 224, 5);
    k_wt<<<nb(128L * 224 * 5), 256, 0, stream>>>(gq1_w, wgq1, 128, 128, 224, 5);
    k_wt<<<nb(128L * 224 * 5), 256, 0, stream>>>(gz2_w, wgz2, 128, 128, 224, 5);
    k_wt<<<nb(128L * 224 * 5), 256, 0, stream>>>(gr2_w, wgr2, 128, 128, 224, 5);
    k_wt<<<nb(128L * 224 * 5), 256, 0, stream>>>(gq2_w, wgq2, 128, 128, 224, 5);
    k_wt<<<nb(256L * 128), 256, 0, stream>>>(fh_w1, wfh1, 256, 256, 128, 1);
    k_wt<<<nb(49L * 49), 256, 0, stream>>>(dap_w, wdap, 49, 49, 49, 1);

    // ---- warp + channel-sum ----
    k_warp<<<nb(BB * HWW), 256, 0, stream>>>(fmap2, flow, f2w, cs);

    // ---- matching net in chunks of CH displacement-batches ----
    for (int n0 = 0; n0 < 98; n0 += CH) {
        dim3 g1(nb((long)CH * HWW), 6);       // 96/16
        k_conv1t<16><<<g1, 256, 0, stream>>>(fmap1, f2w, cs, wt1, mn_b1, x1, n0, CH);
        dim3 g2(nb((long)CH * 1536), 16);     // 128/8
        k_convg<3,3,1,1,2,8,1><<<g2, 256, 0, stream>>>(x1, wt2, mn_b2, x2, CH, 96, 128, 128, 64, 96, 32, 48);
        dim3 g3(nb((long)CH * 1536), 16);
        k_convg<3,3,1,1,1,8,1><<<g3, 256, 0, stream>>>(x2, wt3, mn_b3, x3, CH, 128, 128, 128, 32, 48, 32, 48);
        dim3 g4(nb((long)CH * 1536), 8);      // 64/8
        k_convg<3,3,1,1,1,8,1><<<g4, 256, 0, stream>>>(x3, wt4, mn_b4, x4, CH, 128, 64, 64, 32, 48, 32, 48);
        dim3 gd(nb((long)CH * 1536), 4);      // 32/8
        k_deconvt<8><<<gd, 256, 0, stream>>>(x4, wtd, mn_bd, x5, CH);
        k_conv5v<<<nb((long)CH * 1536), 256, 0, stream>>>(x5, mn_w5, mn_b5, cvol + (long)n0 * HWW, CH);
    }

    // ---- DAP + motion-encoder input assembly ----
    k_dapt<<<nb((long)BB * HWW), 256, 0, stream>>>(cvol, wdap, dap_b, mein);
    k_me_tail<<<nb((long)BB * 34 * HWW), 256, 0, stream>>>(fmap1, flow, mein);

    // ---- motion encoder ----
    dim3 gme(nb((long)BB * HWW), 16);
    k_convg<3,3,1,1,1,8,2><<<gme, 256, 0, stream>>>(mein, wme1, me_b1, m1, BB, 83, 128, 128, 64, 96, 64, 96);
    k_convg<3,3,1,1,1,8,2><<<gme, 256, 0, stream>>>(m1, wme2, me_b2, m2, BB, 128, 128, 128, 64, 96, 64, 96);
    dim3 gme3(nb((long)BB * HWW), 12);        // ceil(94/8)
    k_convg<3,3,1,1,1,8,0><<<gme3, 256, 0, stream>>>(m2, wme3, me_b3, m3, BB, 128, 94, 96, 64, 96, 64, 96);

    // ---- GRU 1 (horizontal 1x5) ----
    k_set_head<<<nb((long)BB * HID * HWW), 256, 0, stream>>>(hx, h);
    k_set_tails<<<nb((long)BB * 96 * HWW), 256, 0, stream>>>(hx, hx2, m3, flow);
    dim3 ggr(nb((long)BB * HWW), 16);
    k_gru_zrt<0,8><<<ggr, 256, 0, stream>>>(hx, wgz1, gz1_b, wgr1, gr1_b, h, zb, hx2);
    k_gru_qt<0,8><<<ggr, 256, 0, stream>>>(hx2, wgq1, gq1_b, zb, h, h1);

    // ---- GRU 2 (vertical 5x1) ----
    k_set_head<<<nb((long)BB * HID * HWW), 256, 0, stream>>>(hx, h1);
    k_gru_zrt<1,8><<<ggr, 256, 0, stream>>>(hx, wgz2, gz2_b, wgr2, gr2_b, h1, zb, hx2);
    k_gru_qt<1,8><<<ggr, 256, 0, stream>>>(hx2, wgq2, gq2_b, zb, h1, outH);

    // ---- flow head ----
    dim3 gfh(nb((long)BB * HWW), 32);         // 256/8
    k_convg<1,1,0,0,1,8,2><<<gfh, 256, 0, stream>>>(outH, wfh1, fh_b1, s1, BB, 128, 256, 256, 64, 96, 64, 96);
    k_fh2<<<nb((long)BB * HWW), 256, 0, stream>>>(s1, fh_w2, fh_b2, flow, outFlow);
}

// Round 5
// 1178.570 us; speedup vs baseline: 32.7700x; 3.4810x over previous
//
#include <hip/hip_runtime.h>
#include <math.h>

typedef unsigned short u16;
typedef unsigned int u32;
typedef __attribute__((ext_vector_type(8))) short bf16x8;
typedef __attribute__((ext_vector_type(4))) float f32x4;

#define HWW 6144

__device__ __forceinline__ float sigmoidf_(float x) { return 1.f / (1.f + expf(-x)); }
__device__ __forceinline__ float lrelu_(float x) { return x >= 0.f ? x : 0.01f * x; }
__device__ __forceinline__ u16 f2bf(float f) {
    u32 u = __float_as_uint(f);
    u += 0x7fffu + ((u >> 16) & 1u);
    return (u16)(u >> 16);
}
__device__ __forceinline__ float bf2f(u16 h) { return __uint_as_float(((u32)h) << 16); }
__device__ __forceinline__ u32 pk2(float a, float b) { return (u32)f2bf(a) | ((u32)f2bf(b) << 16); }

// ======== weight preps ========
__global__ __launch_bounds__(256) void k_wt_bf(const float* __restrict__ w, u16* __restrict__ dst,
                                               int OC, int rowOff, int IC, int ICP, int NT)
{
    int i = blockIdx.x * 256 + threadIdx.x;
    int tot = OC * NT * ICP;
    if (i >= tot) return;
    int c = i % ICP; int t = (i / ICP) % NT; int o = i / (ICP * NT);
    float val = (c < IC) ? w[((long)o * IC + c) * NT + t] : 0.f;
    dst[((long)(rowOff + o) * NT + t) * ICP + c] = f2bf(val);
}

__global__ __launch_bounds__(256) void k_wt_dq(const float* __restrict__ w, u16* __restrict__ dst)
{
    int i = blockIdx.x * 256 + threadIdx.x;
    if (i >= 32768) return;
    int c = i & 63; int t = (i >> 6) & 3; int o = (i >> 8) & 31; int q = i >> 13;
    int ry = q >> 1, rx = q & 1, ta = t >> 1, tb = t & 1;
    int ky = ry + 2 * ta, kx = rx + 2 * tb;
    float val = w[(((long)o * 64 + c) * 4 + ky) * 4 + kx];
    dst[(long)q * 8192 + o * 256 + t * 64 + c] = f2bf(val);
}

__global__ __launch_bounds__(256) void k_wt5(const float* __restrict__ w, float* __restrict__ wt)
{
    int i = blockIdx.x * 256 + threadIdx.x;
    if (i >= 288) return;
    int t = i % 9, c = i / 9;
    wt[t * 32 + c] = w[c * 9 + t];
}

__global__ void k_catb(const float* __restrict__ a, const float* __restrict__ b, float* __restrict__ d)
{
    int i = threadIdx.x;
    if (i < 128) d[i] = a[i];
    else if (i < 256) d[i] = b[i - 128];
}

// ======== elementwise / prep kernels ========
__global__ __launch_bounds__(64) void k_prep_f1(const float* __restrict__ fmap1, u16* __restrict__ f1bf)
{
    int idx = blockIdx.x * 64 + threadIdx.x;
    if (idx >= 12288) return;
    int b = idx / HWW, p = idx % HWW;
    const float* fb = fmap1 + (long)b * 32 * HWW + p;
    u32 pk[16];
    #pragma unroll
    for (int c2 = 0; c2 < 16; ++c2)
        pk[c2] = pk2(fb[(long)(2 * c2) * HWW], fb[(long)(2 * c2 + 1) * HWW]);
    u16* op = f1bf + ((long)idx << 5);
    #pragma unroll
    for (int q = 0; q < 4; ++q)
        ((uint4*)op)[q] = make_uint4(pk[4 * q], pk[4 * q + 1], pk[4 * q + 2], pk[4 * q + 3]);
}

__global__ __launch_bounds__(64) void k_warp(const float* __restrict__ fmap2, const float* __restrict__ flow,
                                             u16* __restrict__ f2wbf, float* __restrict__ cs)
{
    int idx = blockIdx.x * 64 + threadIdx.x;
    if (idx >= 12288) return;
    int b = idx / HWW, p = idx % HWW, y = p / 96, x = p % 96;
    float u = flow[(b * 2 + 0) * HWW + p], v = flow[(b * 2 + 1) * HWW + p];
    float fx = (float)x + u, fy = (float)y + v;
    float fx0 = floorf(fx), fy0 = floorf(fy);
    float wx = fx - fx0, wy = fy - fy0;
    int x0 = (int)fx0, y0i = (int)fy0, x1 = x0 + 1, y1 = y0i + 1;
    bool vx0 = x0 >= 0 && x0 < 96, vx1 = x1 >= 0 && x1 < 96;
    bool vy0 = y0i >= 0 && y0i < 64, vy1 = y1 >= 0 && y1 < 64;
    float m00 = (vy0 && vx0) ? (1.f - wy) * (1.f - wx) : 0.f;
    float m01 = (vy0 && vx1) ? (1.f - wy) * wx : 0.f;
    float m10 = (vy1 && vx0) ? wy * (1.f - wx) : 0.f;
    float m11 = (vy1 && vx1) ? wy * wx : 0.f;
    int cx0 = min(max(x0, 0), 95), cx1 = min(max(x1, 0), 95);
    int cy0 = min(max(y0i, 0), 63), cy1 = min(max(y1, 0), 63);
    int i00 = cy0 * 96 + cx0, i01 = cy0 * 96 + cx1, i10 = cy1 * 96 + cx0, i11 = cy1 * 96 + cx1;
    const float* fb = fmap2 + (long)b * 32 * HWW;
    float s = 0.f; u32 pk[16];
    #pragma unroll
    for (int c2 = 0; c2 < 16; ++c2) {
        const float* fa = fb + (long)(2 * c2) * HWW;
        const float* fc = fb + (long)(2 * c2 + 1) * HWW;
        float g0 = m00 * fa[i00] + m01 * fa[i01] + m10 * fa[i10] + m11 * fa[i11];
        float g1 = m00 * fc[i00] + m01 * fc[i01] + m10 * fc[i10] + m11 * fc[i11];
        s += g0 + g1;
        pk[c2] = pk2(g0, g1);
    }
    u16* op = f2wbf + ((long)idx << 5);
    #pragma unroll
    for (int q = 0; q < 4; ++q)
        ((uint4*)op)[q] = make_uint4(pk[4 * q], pk[4 * q + 1], pk[4 * q + 2], pk[4 * q + 3]);
    cs[idx] = s;
}

// ======== MFMA implicit GEMM ========
// MODE 0: standard conv over NHWC bf16, taps (KH,KW,PH,PW), stride STRIDE
// MODE 1: conv1 fused mvol (A0=f1bf, A1=f2wbf, csm mask); nOff = displacement-batch offset
// MODE 2: deconv quadrant (blockIdx.z = ry*2+rx)
template<int BN, int MODE, int KH, int KW, int PH, int PW, int STRIDE, int ACT, int OUTF32>
__global__ __launch_bounds__(256) void k_gemm(
    const u16* __restrict__ A0, const u16* __restrict__ A1,
    const float* __restrict__ csm, const u16* __restrict__ Wb,
    const float* __restrict__ bias,
    u16* __restrict__ outb, u16* __restrict__ outb2, float* __restrict__ outf,
    int IH, int IW, int OH, int OW, int ICP, int NKT, int OC, int ldc, int coff, int nOff)
{
    constexpr int WAVES_M = (BN == 128) ? 2 : 4;
    constexpr int WTM = 128 / WAVES_M;
    constexpr int WTN = (BN == 128) ? 64 : BN;
    constexpr int MF = WTM / 16;
    constexpr int NF = WTN / 16;
    __shared__ u16 As[128 * 40];
    __shared__ u16 Bs[BN * 40];
    int tid = threadIdx.x;
    int mrow = tid >> 1;
    int khOff = (tid & 1) << 4;
    long gmS = (long)blockIdx.x * 128 + mrow;
    int nImg, y0, x0, bImg = 0, diS = 0, djS = 0, ryz = 0, rxz = 0;
    {
        int ohw = (MODE == 1) ? 6144 : ((MODE == 2) ? 1536 : OH * OW);
        int ow = (MODE == 1) ? 96 : ((MODE == 2) ? 48 : OW);
        nImg = (int)(gmS / ohw);
        int rem = (int)(gmS - (long)nImg * ohw);
        y0 = rem / ow; x0 = rem - y0 * ow;
        if (MODE == 1) {
            int n = nOff + nImg;
            bImg = n / 49; int kd = n - bImg * 49; diS = kd / 7 - 3; djS = kd % 7 - 3;
        }
        if (MODE == 2) { ryz = blockIdx.z >> 1; rxz = blockIdx.z & 1; }
    }
    const u16* WbZ = Wb;
    if (MODE == 2) WbZ += (long)blockIdx.z * 32 * 256;
    int n0 = blockIdx.y * BN;
    int lane = tid & 63, wid = tid >> 6;
    int wm = (BN == 128) ? (wid >> 1) : wid;
    int wn = (BN == 128) ? (wid & 1) : 0;
    int fr = lane & 15, fg = lane >> 4;
    f32x4 acc[MF][NF];
    #pragma unroll
    for (int i = 0; i < MF; ++i)
        #pragma unroll
        for (int j = 0; j < NF; ++j)
            acc[i][j] = (f32x4){0.f, 0.f, 0.f, 0.f};
    const int KTC = ICP >> 5;
    for (int kt = 0; kt < NKT; ++kt) {
        uint4 va0 = {0u,0u,0u,0u}, va1 = {0u,0u,0u,0u};
        if (MODE == 0) {
            int t = kt / KTC; int c0 = (kt - t * KTC) << 5;
            int dy = t / KW - PH, dx = t - (t / KW) * KW - PW;
            int iy = y0 * STRIDE + dy, ix = x0 * STRIDE + dx;
            if (iy >= 0 && iy < IH && ix >= 0 && ix < IW) {
                const u16* sp = A0 + ((long)(nImg * IH + iy) * IW + ix) * ICP + c0 + khOff;
                va0 = *(const uint4*)sp; va1 = *(const uint4*)(sp + 8);
            }
        } else if (MODE == 1) {
            int t = kt >> 1, half = kt & 1;
            int dy = t / 3 - 1, dx = t % 3 - 1;
            int yy = y0 + dy, xx = x0 + dx, ys = yy + djS, xs = xx + diS;
            if (yy >= 0 && yy < 64 && xx >= 0 && xx < 96 && ys >= 0 && ys < 64 && xs >= 0 && xs < 96) {
                if (csm[bImg * HWW + ys * 96 + xs] != 0.f) {
                    const u16* sp = half ? (A1 + (((long)bImg * HWW + ys * 96 + xs) << 5) + khOff)
                                         : (A0 + (((long)bImg * HWW + yy * 96 + xx) << 5) + khOff);
                    va0 = *(const uint4*)sp; va1 = *(const uint4*)(sp + 8);
                }
            }
        } else {
            int t = kt >> 1, c0 = (kt & 1) << 5;
            int ta = t >> 1, tb = t & 1;
            int iy = y0 + ryz + ta - 1, ix = x0 + rxz + tb - 1;
            if (iy >= 0 && iy < 32 && ix >= 0 && ix < 48) {
                const u16* sp = A0 + (((long)(nImg * 32 + iy) * 48 + ix) << 6) + c0 + khOff;
                va0 = *(const uint4*)sp; va1 = *(const uint4*)(sp + 8);
            }
        }
        *(uint4*)&As[mrow * 40 + khOff] = va0;
        *(uint4*)&As[mrow * 40 + khOff + 8] = va1;
        if (tid < 2 * BN) {
            int brow = tid >> 1; int ko = (tid & 1) << 4;
            const u16* wp = WbZ + (long)(n0 + brow) * (NKT * 32) + kt * 32 + ko;
            *(uint4*)&Bs[brow * 40 + ko] = *(const uint4*)wp;
            *(uint4*)&Bs[brow * 40 + ko + 8] = *(const uint4*)(wp + 8);
        }
        __syncthreads();
        bf16x8 af[MF], bfv[NF];
        #pragma unroll
        for (int i = 0; i < MF; ++i)
            af[i] = *(const bf16x8*)&As[(wm * WTM + i * 16 + fr) * 40 + fg * 8];
        #pragma unroll
        for (int j = 0; j < NF; ++j)
            bfv[j] = *(const bf16x8*)&Bs[(wn * WTN + j * 16 + fr) * 40 + fg * 8];
        #pragma unroll
        for (int i = 0; i < MF; ++i)
            #pragma unroll
            for (int j = 0; j < NF; ++j)
                acc[i][j] = __builtin_amdgcn_mfma_f32_16x16x32_bf16(af[i], bfv[j], acc[i][j], 0, 0, 0);
        __syncthreads();
    }
    // epilogue
    #pragma unroll
    for (int i = 0; i < MF; ++i) {
        #pragma unroll
        for (int j = 0; j < NF; ++j) {
            int nn = n0 + wn * WTN + j * 16 + fr;
            if (nn >= OC) continue;
            #pragma unroll
            for (int rr = 0; rr < 4; ++rr) {
                int mloc = wm * WTM + i * 16 + fg * 4 + rr;
                long gm = (long)blockIdx.x * 128 + mloc;
                float v = acc[i][j][rr] + bias[nn];
                if (ACT == 1) v = fmaxf(v, 0.f);
                else if (ACT == 2) v = lrelu_(v);
                if (OUTF32) {
                    outf[gm * ldc + coff + nn] = v;
                } else if (MODE == 2) {
                    int nI = (int)(gm / 1536); int rq = (int)(gm - (long)nI * 1536);
                    int Y = rq / 48, X = rq - (rq / 48) * 48;
                    long di = (((long)nI * 64 + 2 * Y + ryz) * 96 + (2 * X + rxz)) * 32 + nn;
                    outb[di] = f2bf(v);
                } else {
                    long di = gm * ldc + coff + nn;
                    u16 hv = f2bf(v);
                    outb[di] = hv;
                    if (outb2) outb2[di] = hv;
                }
            }
        }
    }
}

// ======== conv5 (32->1, 3x3) scalar over NHWC bf16 ========
__global__ __launch_bounds__(256) void k_conv5n(const u16* __restrict__ x5, const float* __restrict__ w5t,
                                                const float* __restrict__ b5, float* __restrict__ cvol, int N)
{
    int idx = blockIdx.x * 256 + threadIdx.x;
    if (idx >= N * HWW) return;
    int n = idx / HWW, p = idx % HWW, y = p / 96, x = p % 96;
    float acc = b5[0];
    #pragma unroll
    for (int t = 0; t < 9; ++t) {
        int iy = y + t / 3 - 1, ix = x + t % 3 - 1;
        if (iy < 0 || iy >= 64 || ix < 0 || ix >= 96) continue;
        const u16* sp = x5 + (((long)n * HWW + iy * 96 + ix) << 5);
        const float* wt_ = w5t + t * 32;
        #pragma unroll
        for (int c8 = 0; c8 < 4; ++c8) {
            uint4 v = *(const uint4*)(sp + c8 * 8);
            acc = fmaf(bf2f((u16)(v.x & 0xffffu)), wt_[c8 * 8 + 0], acc);
            acc = fmaf(bf2f((u16)(v.x >> 16)),     wt_[c8 * 8 + 1], acc);
            acc = fmaf(bf2f((u16)(v.y & 0xffffu)), wt_[c8 * 8 + 2], acc);
            acc = fmaf(bf2f((u16)(v.y >> 16)),     wt_[c8 * 8 + 3], acc);
            acc = fmaf(bf2f((u16)(v.z & 0xffffu)), wt_[c8 * 8 + 4], acc);
            acc = fmaf(bf2f((u16)(v.z >> 16)),     wt_[c8 * 8 + 5], acc);
            acc = fmaf(bf2f((u16)(v.w & 0xffffu)), wt_[c8 * 8 + 6], acc);
            acc = fmaf(bf2f((u16)(v.w >> 16)),     wt_[c8 * 8 + 7], acc);
        }
    }
    cvol[idx] = acc;
}

// ======== DAP: 49x49 over displacement channels, writes mein ch 0..48 (NHWC bf16) ========
__global__ __launch_bounds__(64) void k_dapt(const float* __restrict__ cvol, const float* __restrict__ dw,
                                             const float* __restrict__ db, u16* __restrict__ mein)
{
    int idx = blockIdx.x * 64 + threadIdx.x;
    if (idx >= 12288) return;
    int b = idx / HWW, p = idx % HWW;
    float acc[49];
    #pragma unroll
    for (int o = 0; o < 49; ++o) acc[o] = db[o];
    const float* cb = cvol + (long)b * 49 * HWW + p;
    for (int k = 0; k < 49; ++k) {
        float v = cb[(long)k * HWW];
        #pragma unroll
        for (int o = 0; o < 49; ++o) acc[o] = fmaf(dw[o * 49 + k], v, acc[o]);
    }
    u16* mp = mein + (long)idx * 96;
    #pragma unroll
    for (int o = 0; o < 49; ++o) mp[o] = f2bf(acc[o]);
}

// ======== mein ch 49..82 = fmap1 + flow, 83..95 = 0 ========
__global__ __launch_bounds__(64) void k_me_tail(const float* __restrict__ fmap1, const float* __restrict__ flow,
                                                u16* __restrict__ mein)
{
    int idx = blockIdx.x * 64 + threadIdx.x;
    if (idx >= 12288) return;
    int b = idx / HWW, p = idx % HWW;
    u16* mp = mein + (long)idx * 96;
    #pragma unroll
    for (int c = 0; c < 32; ++c)
        mp[49 + c] = f2bf(fmap1[((long)(b * 32 + c)) * HWW + p]);
    mp[81] = f2bf(flow[(b * 2 + 0) * HWW + p]);
    mp[82] = f2bf(flow[(b * 2 + 1) * HWW + p]);
    #pragma unroll
    for (int c = 83; c < 96; ++c) mp[c] = 0;
}

// ======== set hx head from h (NCHW f32) + hst copy (NHWC f32) ========
__global__ __launch_bounds__(64) void k_set_head(const float* __restrict__ h, float* __restrict__ hst,
                                                 u16* __restrict__ hx)
{
    int idx = blockIdx.x * 64 + threadIdx.x;
    if (idx >= 12288) return;
    int b = idx / HWW, p = idx % HWW;
    const float* hp = h + (long)b * 128 * HWW + p;
    float* hs = hst + (long)idx * 128;
    u16* hxp = hx + (long)idx * 224;
    #pragma unroll 4
    for (int c = 0; c < 128; c += 8) {
        float v[8];
        #pragma unroll
        for (int q = 0; q < 8; ++q) v[q] = hp[(long)(c + q) * HWW];
        *(float4*)&hs[c] = make_float4(v[0], v[1], v[2], v[3]);
        *(float4*)&hs[c + 4] = make_float4(v[4], v[5], v[6], v[7]);
        uint4 pk = make_uint4(pk2(v[0], v[1]), pk2(v[2], v[3]), pk2(v[4], v[5]), pk2(v[6], v[7]));
        *(uint4*)&hxp[c] = pk;
    }
}

// ======== flow -> hx/hx2 channels 222,223 ========
__global__ __launch_bounds__(64) void k_set_tails_f(const float* __restrict__ flow,
                                                    u16* __restrict__ hx, u16* __restrict__ hx2)
{
    int idx = blockIdx.x * 64 + threadIdx.x;
    if (idx >= 12288) return;
    int b = idx / HWW, p = idx % HWW;
    u16 uu = f2bf(flow[(b * 2 + 0) * HWW + p]);
    u16 vv = f2bf(flow[(b * 2 + 1) * HWW + p]);
    long o = (long)idx * 224;
    hx[o + 222] = uu; hx[o + 223] = vv;
    hx2[o + 222] = uu; hx2[o + 223] = vv;
}

// ======== GRU post z/r: z = sig(az); hx2 head = sig(ar)*hst ========
__global__ __launch_bounds__(64) void k_post_zr(const float* __restrict__ azr, const float* __restrict__ hst,
                                                float* __restrict__ z, u16* __restrict__ hx2)
{
    int idx = blockIdx.x * 64 + threadIdx.x;
    if (idx >= 12288) return;
    const float* ap = azr + (long)idx * 256;
    const float* hs = hst + (long)idx * 128;
    float* zp = z + (long)idx * 128;
    u16* xp = hx2 + (long)idx * 224;
    #pragma unroll 4
    for (int c = 0; c < 128; c += 8) {
        float4 a0 = *(const float4*)&ap[c], a1 = *(const float4*)&ap[c + 4];
        float4 r0 = *(const float4*)&ap[128 + c], r1 = *(const float4*)&ap[128 + c + 4];
        float4 h0 = *(const float4*)&hs[c], h1v = *(const float4*)&hs[c + 4];
        float z0 = sigmoidf_(a0.x), z1 = sigmoidf_(a0.y), z2 = sigmoidf_(a0.z), z3 = sigmoidf_(a0.w);
        float z4 = sigmoidf_(a1.x), z5 = sigmoidf_(a1.y), z6 = sigmoidf_(a1.z), z7 = sigmoidf_(a1.w);
        *(float4*)&zp[c] = make_float4(z0, z1, z2, z3);
        *(float4*)&zp[c + 4] = make_float4(z4, z5, z6, z7);
        float rh0 = sigmoidf_(r0.x) * h0.x, rh1 = sigmoidf_(r0.y) * h0.y;
        float rh2 = sigmoidf_(r0.z) * h0.z, rh3 = sigmoidf_(r0.w) * h0.w;
        float rh4 = sigmoidf_(r1.x) * h1v.x, rh5 = sigmoidf_(r1.y) * h1v.y;
        float rh6 = sigmoidf_(r1.z) * h1v.z, rh7 = sigmoidf_(r1.w) * h1v.w;
        uint4 pk = make_uint4(pk2(rh0, rh1), pk2(rh2, rh3), pk2(rh4, rh5), pk2(rh6, rh7));
        *(uint4*)&xp[c] = pk;
    }
}

// ======== GRU post q: hnew = (1-z)h + z tanh(aq). FIN=0 -> h1f+hx head; FIN=1 -> outH(NCHW)+h2bf ========
template<int FIN>
__global__ __launch_bounds__(64) void k_post_q(const float* __restrict__ aq, const float* __restrict__ z,
                                               const float* __restrict__ hst, float* __restrict__ h1f,
                                               u16* __restrict__ hxdst, float* __restrict__ outH)
{
    int idx = blockIdx.x * 64 + threadIdx.x;
    if (idx >= 12288) return;
    int b = idx / HWW, p = idx % HWW;
    const float* ap = aq + (long)idx * 128;
    const float* zp = z + (long)idx * 128;
    const float* hs = hst + (long)idx * 128;
    #pragma unroll 4
    for (int c = 0; c < 128; c += 8) {
        float hn[8];
        #pragma unroll
        for (int q = 0; q < 8; ++q) {
            float qq = tanhf(ap[c + q]);
            float zv = zp[c + q];
            hn[q] = (1.f - zv) * hs[c + q] + zv * qq;
        }
        if (FIN == 0) {
            *(float4*)&h1f[(long)idx * 128 + c] = make_float4(hn[0], hn[1], hn[2], hn[3]);
            *(float4*)&h1f[(long)idx * 128 + c + 4] = make_float4(hn[4], hn[5], hn[6], hn[7]);
            uint4 pk = make_uint4(pk2(hn[0], hn[1]), pk2(hn[2], hn[3]), pk2(hn[4], hn[5]), pk2(hn[6], hn[7]));
            *(uint4*)&hxdst[(long)idx * 224 + c] = pk;
        } else {
            #pragma unroll
            for (int q = 0; q < 8; ++q)
                outH[((long)(b * 128 + c + q)) * HWW + p] = hn[q];
            uint4 pk = make_uint4(pk2(hn[0], hn[1]), pk2(hn[2], hn[3]), pk2(hn[4], hn[5]), pk2(hn[6], hn[7]));
            *(uint4*)&hxdst[(long)idx * 128 + c] = pk;
        }
    }
}

// ======== flow head layer 2 + softmax + expectation (s1 NHWC f32) ========
__global__ __launch_bounds__(64) void k_fh2(const float* __restrict__ s1, const float* __restrict__ w,
                                            const float* __restrict__ bias, const float* __restrict__ flow,
                                            float* __restrict__ outFlow)
{
    int idx = blockIdx.x * 64 + threadIdx.x;
    if (idx >= 12288) return;
    int b = idx / HWW, p = idx % HWW;
    float lg[49];
    #pragma unroll
    for (int k = 0; k < 49; ++k) lg[k] = bias[k];
    const float* sp = s1 + (long)idx * 256;
    for (int c = 0; c < 256; c += 4) {
        float4 v = *(const float4*)&sp[c];
        #pragma unroll
        for (int k = 0; k < 49; ++k) {
            const float* wr = w + k * 256 + c;
            lg[k] = fmaf(wr[0], v.x, fmaf(wr[1], v.y, fmaf(wr[2], v.z, fmaf(wr[3], v.w, lg[k]))));
        }
    }
    float m = -1e30f;
    #pragma unroll
    for (int k = 0; k < 49; ++k) { lg[k] = lrelu_(lg[k]); m = fmaxf(m, lg[k]); }
    float s = 0.f, a0 = 0.f, a1 = 0.f;
    #pragma unroll
    for (int k = 0; k < 49; ++k) {
        float e = expf(lg[k] - m);
        s += e;
        a0 += e * (float)(k / 7 - 3);
        a1 += e * (float)(k % 7 - 3);
    }
    float inv = 1.f / s;
    outFlow[(long)(b * 2 + 0) * HWW + p] = flow[(long)(b * 2 + 0) * HWW + p] + a0 * inv;
    outFlow[(long)(b * 2 + 1) * HWW + p] = flow[(long)(b * 2 + 1) * HWW + p] + a1 * inv;
}

extern "C" void kernel_launch(void* const* d_in, const int* in_sizes, int n_in,
                              void* d_out, int out_size, void* d_ws, size_t ws_size,
                              hipStream_t stream)
{
    const float* fmap1 = (const float*)d_in[0];
    const float* fmap2 = (const float*)d_in[1];
    const float* h     = (const float*)d_in[2];
    const float* flow  = (const float*)d_in[3];
    int pb = (in_sizes[4] == 1) ? 5 : 4;
    const float* mn_w1 = (const float*)d_in[pb + 0];
    const float* mn_b1 = (const float*)d_in[pb + 1];
    const float* mn_w2 = (const float*)d_in[pb + 2];
    const float* mn_b2 = (const float*)d_in[pb + 3];
    const float* mn_w3 = (const float*)d_in[pb + 4];
    const float* mn_b3 = (const float*)d_in[pb + 5];
    const float* mn_w4 = (const float*)d_in[pb + 6];
    const float* mn_b4 = (const float*)d_in[pb + 7];
    const float* mn_wd = (const float*)d_in[pb + 8];
    const float* mn_bd = (const float*)d_in[pb + 9];
    const float* mn_w5 = (const float*)d_in[pb + 10];
    const float* mn_b5 = (const float*)d_in[pb + 11];
    const float* dap_w = (const float*)d_in[pb + 12];
    const float* dap_b = (const float*)d_in[pb + 13];
    const float* me_w1 = (const float*)d_in[pb + 14];
    const float* me_b1 = (const float*)d_in[pb + 15];
    const float* me_w2 = (const float*)d_in[pb + 16];
    const float* me_b2 = (const float*)d_in[pb + 17];
    const float* me_w3 = (const float*)d_in[pb + 18];
    const float* me_b3 = (const float*)d_in[pb + 19];
    const float* gz1_w = (const float*)d_in[pb + 20];
    const float* gz1_b = (const float*)d_in[pb + 21];
    const float* gr1_w = (const float*)d_in[pb + 22];
    const float* gr1_b = (const float*)d_in[pb + 23];
    const float* gq1_w = (const float*)d_in[pb + 24];
    const float* gq1_b = (const float*)d_in[pb + 25];
    const float* gz2_w = (const float*)d_in[pb + 26];
    const float* gz2_b = (const float*)d_in[pb + 27];
    const float* gr2_w = (const float*)d_in[pb + 28];
    const float* gr2_b = (const float*)d_in[pb + 29];
    const float* gq2_w = (const float*)d_in[pb + 30];
    const float* gq2_b = (const float*)d_in[pb + 31];
    const float* fh_w1 = (const float*)d_in[pb + 32];
    const float* fh_b1 = (const float*)d_in[pb + 33];
    const float* fh_w2 = (const float*)d_in[pb + 34];
    const float* fh_b2 = (const float*)d_in[pb + 35];

    char* wsB = (char*)d_ws;
    size_t off = 0;
    auto alc = [&](size_t bytes) { size_t o = off; off = (off + bytes + 255) & ~(size_t)255; return o; };

    // ---- weight arena (memset to 0 first) ----
    size_t o_wc1  = alc(128 * 576 * 2);
    size_t o_wc2  = alc(128 * 864 * 2);
    size_t o_wc3  = alc((size_t)128 * 1152 * 2);
    size_t o_wc4  = alc((size_t)64 * 1152 * 2);
    size_t o_wdq  = alc(32768 * 2);
    size_t o_wme1 = alc(128 * 864 * 2);
    size_t o_wme2 = alc((size_t)128 * 1152 * 2);
    size_t o_wme3 = alc((size_t)128 * 1152 * 2);
    size_t o_wzr1 = alc((size_t)256 * 1120 * 2);
    size_t o_wq1  = alc((size_t)128 * 1120 * 2);
    size_t o_wzr2 = alc((size_t)256 * 1120 * 2);
    size_t o_wq2  = alc((size_t)128 * 1120 * 2);
    size_t o_wfh1 = alc(256 * 128 * 2);
    size_t o_w5t  = alc(288 * 4);
    size_t o_bzr1 = alc(256 * 4);
    size_t o_bzr2 = alc(256 * 4);
    size_t wArenaBytes = off;

    // ---- persistent activations (span both phases) ----
    size_t o_f1bf = alc((size_t)12288 * 32 * 2);
    size_t o_f2wb = alc((size_t)12288 * 32 * 2);
    size_t o_cs   = alc(12288 * 4);
    size_t o_cvol = alc((size_t)98 * 6144 * 4);

    // ---- shared region: phase-A x-scratch (CH=49) overlaid with phase-B buffers ----
    const int CH = 49;
    size_t sharedBase = off;
    // phase A sub-layout
    size_t offA = sharedBase;
    auto alcA = [&](size_t bytes) { size_t o = offA; offA = (offA + bytes + 255) & ~(size_t)255; return o; };
    size_t o_x1 = alcA((size_t)CH * 6144 * 96 * 2);
    size_t o_x2 = alcA((size_t)CH * 1536 * 128 * 2);
    size_t o_x3 = alcA((size_t)CH * 1536 * 128 * 2);
    size_t o_x4 = alcA((size_t)CH * 1536 * 64 * 2);
    size_t o_x5 = alcA((size_t)CH * 6144 * 32 * 2);
    // phase B sub-layout
    size_t offB2 = sharedBase;
    auto alcB = [&](size_t bytes) { size_t o = offB2; offB2 = (offB2 + bytes + 255) & ~(size_t)255; return o; };
    size_t o_mein = alcB((size_t)12288 * 96 * 2);
    size_t o_m1   = alcB((size_t)12288 * 128 * 2);
    size_t o_m2   = alcB((size_t)12288 * 128 * 2);
    size_t o_hx   = alcB((size_t)12288 * 224 * 2);
    size_t o_hx2  = alcB((size_t)12288 * 224 * 2);
    size_t o_h2bf = alcB((size_t)12288 * 128 * 2);
    size_t o_hst  = alcB((size_t)12288 * 128 * 4);
    size_t o_h1f  = alcB((size_t)12288 * 128 * 4);
    size_t o_zf   = alcB((size_t)12288 * 128 * 4);
    size_t o_azr  = alcB((size_t)12288 * 256 * 4);
    size_t o_aqf  = alcB((size_t)12288 * 128 * 4);
    size_t o_s1   = alcB((size_t)12288 * 256 * 4);
    // total = sharedBase + max(phaseA, phaseB)  ~ 133 MB < ws_size

    u16* wc1  = (u16*)(wsB + o_wc1);   u16* wc2  = (u16*)(wsB + o_wc2);
    u16* wc3  = (u16*)(wsB + o_wc3);   u16* wc4  = (u16*)(wsB + o_wc4);
    u16* wdq  = (u16*)(wsB + o_wdq);
    u16* wme1 = (u16*)(wsB + o_wme1);  u16* wme2 = (u16*)(wsB + o_wme2);
    u16* wme3 = (u16*)(wsB + o_wme3);
    u16* wzr1 = (u16*)(wsB + o_wzr1);  u16* wq1  = (u16*)(wsB + o_wq1);
    u16* wzr2 = (u16*)(wsB + o_wzr2);  u16* wq2  = (u16*)(wsB + o_wq2);
    u16* wfh1 = (u16*)(wsB + o_wfh1);
    float* w5t = (float*)(wsB + o_w5t);
    float* bzr1 = (float*)(wsB + o_bzr1);
    float* bzr2 = (float*)(wsB + o_bzr2);

    u16* f1bf = (u16*)(wsB + o_f1bf);  u16* f2wb = (u16*)(wsB + o_f2wb);
    float* cs = (float*)(wsB + o_cs);
    float* cvol = (float*)(wsB + o_cvol);
    u16* x1 = (u16*)(wsB + o_x1); u16* x2 = (u16*)(wsB + o_x2); u16* x3 = (u16*)(wsB + o_x3);
    u16* x4 = (u16*)(wsB + o_x4); u16* x5 = (u16*)(wsB + o_x5);
    u16* mein = (u16*)(wsB + o_mein);
    u16* m1 = (u16*)(wsB + o_m1); u16* m2 = (u16*)(wsB + o_m2);
    u16* hx = (u16*)(wsB + o_hx); u16* hx2 = (u16*)(wsB + o_hx2);
    u16* h2bf = (u16*)(wsB + o_h2bf);
    float* hst = (float*)(wsB + o_hst); float* h1f = (float*)(wsB + o_h1f);
    float* zf = (float*)(wsB + o_zf); float* azr = (float*)(wsB + o_azr);
    float* aqf = (float*)(wsB + o_aqf); float* s1 = (float*)(wsB + o_s1);

    float* outH = (float*)d_out;
    float* outFlow = outH + (long)2 * 128 * HWW;

    auto nb = [](long total, int bs) { return (unsigned)((total + bs - 1) / bs); };

    // ---- weight preps ----
    hipMemsetAsync(wsB, 0, wArenaBytes, stream);
    k_wt_bf<<<nb(96L * 9 * 64, 256), 256, 0, stream>>>(mn_w1, wc1, 96, 0, 64, 64, 9);
    k_wt_bf<<<nb(128L * 9 * 96, 256), 256, 0, stream>>>(mn_w2, wc2, 128, 0, 96, 96, 9);
    k_wt_bf<<<nb(128L * 9 * 128, 256), 256, 0, stream>>>(mn_w3, wc3, 128, 0, 128, 128, 9);
    k_wt_bf<<<nb(64L * 9 * 128, 256), 256, 0, stream>>>(mn_w4, wc4, 64, 0, 128, 128, 9);
    k_wt_dq<<<nb(32768, 256), 256, 0, stream>>>(mn_wd, wdq);
    k_wt5<<<2, 256, 0, stream>>>(mn_w5, w5t);
    k_wt_bf<<<nb(128L * 9 * 96, 256), 256, 0, stream>>>(me_w1, wme1, 128, 0, 83, 96, 9);
    k_wt_bf<<<nb(128L * 9 * 128, 256), 256, 0, stream>>>(me_w2, wme2, 128, 0, 128, 128, 9);
    k_wt_bf<<<nb(94L * 9 * 128, 256), 256, 0, stream>>>(me_w3, wme3, 94, 0, 128, 128, 9);
    k_wt_bf<<<nb(128L * 5 * 224, 256), 256, 0, stream>>>(gz1_w, wzr1, 128, 0, 224, 224, 5);
    k_wt_bf<<<nb(128L * 5 * 224, 256), 256, 0, stream>>>(gr1_w, wzr1, 128, 128, 224, 224, 5);
    k_wt_bf<<<nb(128L * 5 * 224, 256), 256, 0, stream>>>(gq1_w, wq1, 128, 0, 224, 224, 5);
    k_wt_bf<<<nb(128L * 5 * 224, 256), 256, 0, stream>>>(gz2_w, wzr2, 128, 0, 224, 224, 5);
    k_wt_bf<<<nb(128L * 5 * 224, 256), 256, 0, stream>>>(gr2_w, wzr2, 128, 128, 224, 224, 5);
    k_wt_bf<<<nb(128L * 5 * 224, 256), 256, 0, stream>>>(gq2_w, wq2, 128, 0, 224, 224, 5);
    k_wt_bf<<<nb(256L * 1 * 128, 256), 256, 0, stream>>>(fh_w1, wfh1, 256, 0, 128, 128, 1);
    k_catb<<<1, 256, 0, stream>>>(gz1_b, gr1_b, bzr1);
    k_catb<<<1, 256, 0, stream>>>(gz2_b, gr2_b, bzr2);

    // ---- input preps ----
    k_prep_f1<<<nb(12288, 64), 64, 0, stream>>>(fmap1, f1bf);
    k_warp<<<nb(12288, 64), 64, 0, stream>>>(fmap2, flow, f2wb, cs);

    // ---- matching net: 2 chunks of 49 displacement-batches through shared x-scratch ----
    for (int n0 = 0; n0 < 98; n0 += CH) {
        k_gemm<128,1,3,3,1,1,1,1,0><<<dim3(2352, 1), 256, 0, stream>>>(
            f1bf, f2wb, cs, wc1, mn_b1, x1, nullptr, nullptr, 64, 96, 64, 96, 32, 18, 96, 96, 0, n0);
        k_gemm<128,0,3,3,1,1,2,1,0><<<dim3(588, 1), 256, 0, stream>>>(
            x1, nullptr, nullptr, wc2, mn_b2, x2, nullptr, nullptr, 64, 96, 32, 48, 96, 27, 128, 128, 0, 0);
        k_gemm<128,0,3,3,1,1,1,1,0><<<dim3(588, 1), 256, 0, stream>>>(
            x2, nullptr, nullptr, wc3, mn_b3, x3, nullptr, nullptr, 32, 48, 32, 48, 128, 36, 128, 128, 0, 0);
        k_gemm<64,0,3,3,1,1,1,1,0><<<dim3(588, 1), 256, 0, stream>>>(
            x3, nullptr, nullptr, wc4, mn_b4, x4, nullptr, nullptr, 32, 48, 32, 48, 128, 36, 64, 64, 0, 0);
        k_gemm<32,2,4,4,2,2,1,1,0><<<dim3(588, 1, 4), 256, 0, stream>>>(
            x4, nullptr, nullptr, wdq, mn_bd, x5, nullptr, nullptr, 32, 48, 32, 48, 64, 8, 32, 32, 0, 0);
        k_conv5n<<<nb((long)CH * HWW, 256), 256, 0, stream>>>(x5, w5t, mn_b5, cvol + (long)n0 * HWW, CH);
    }

    // ---- DAP + motion encoder ----
    k_dapt<<<nb(12288, 64), 64, 0, stream>>>(cvol, dap_w, dap_b, mein);
    k_me_tail<<<nb(12288, 64), 64, 0, stream>>>(fmap1, flow, mein);
    k_gemm<128,0,3,3,1,1,1,2,0><<<dim3(96, 1), 256, 0, stream>>>(
        mein, nullptr, nullptr, wme1, me_b1, m1, nullptr, nullptr, 64, 96, 64, 96, 96, 27, 128, 128, 0, 0);
    k_gemm<128,0,3,3,1,1,1,2,0><<<dim3(96, 1), 256, 0, stream>>>(
        m1, nullptr, nullptr, wme2, me_b2, m2, nullptr, nullptr, 64, 96, 64, 96, 128, 36, 128, 128, 0, 0);
    k_gemm<128,0,3,3,1,1,1,0,0><<<dim3(96, 1), 256, 0, stream>>>(
        m2, nullptr, nullptr, wme3, me_b3, hx, hx2, nullptr, 64, 96, 64, 96, 128, 36, 94, 224, 128, 0);

    // ---- GRU 1 (horizontal 1x5) ----
    k_set_head<<<nb(12288, 64), 64, 0, stream>>>(h, hst, hx);
    k_set_tails_f<<<nb(12288, 64), 64, 0, stream>>>(flow, hx, hx2);
    k_gemm<128,0,1,5,0,2,1,0,1><<<dim3(96, 2), 256, 0, stream>>>(
        hx, nullptr, nullptr, wzr1, bzr1, nullptr, nullptr, azr, 64, 96, 64, 96, 224, 35, 256, 256, 0, 0);
    k_post_zr<<<nb(12288, 64), 64, 0, stream>>>(azr, hst, zf, hx2);
    k_gemm<128,0,1,5,0,2,1,0,1><<<dim3(96, 1), 256, 0, stream>>>(
        hx2, nullptr, nullptr, wq1, gq1_b, nullptr, nullptr, aqf, 64, 96, 64, 96, 224, 35, 128, 128, 0, 0);
    k_post_q<0><<<nb(12288, 64), 64, 0, stream>>>(aqf, zf, hst, h1f, hx, nullptr);

    // ---- GRU 2 (vertical 5x1) ----
    k_gemm<128,0,5,1,2,0,1,0,1><<<dim3(96, 2), 256, 0, stream>>>(
        hx, nullptr, nullptr, wzr2, bzr2, nullptr, nullptr, azr, 64, 96, 64, 96, 224, 35, 256, 256, 0, 0);
    k_post_zr<<<nb(12288, 64), 64, 0, stream>>>(azr, h1f, zf, hx2);
    k_gemm<128,0,5,1,2,0,1,0,1><<<dim3(96, 1), 256, 0, stream>>>(
        hx2, nullptr, nullptr, wq2, gq2_b, nullptr, nullptr, aqf, 64, 96, 64, 96, 224, 35, 128, 128, 0, 0);
    k_post_q<1><<<nb(12288, 64), 64, 0, stream>>>(aqf, zf, h1f, nullptr, h2bf, outH);

    // ---- flow head ----
    k_gemm<128,0,1,1,0,0,1,2,1><<<dim3(96, 2), 256, 0, stream>>>(
        h2bf, nullptr, nullptr, wfh1, fh_b1, nullptr, nullptr, s1, 64, 96, 64, 96, 128, 4, 256, 256, 0, 0);
    k_fh2<<<nb(12288, 64), 64, 0, stream>>>(s1, fh_w2, fh_b2, flow, outFlow);
}

// Round 6
// 977.313 us; speedup vs baseline: 39.5183x; 1.2059x over previous
//
#include <hip/hip_runtime.h>
#include <math.h>

typedef unsigned short u16;
typedef unsigned int u32;
typedef __attribute__((ext_vector_type(8))) short bf16x8;
typedef __attribute__((ext_vector_type(4))) float f32x4;

#define HWW 6144

__device__ __forceinline__ float sigmoidf_(float x) { return 1.f / (1.f + expf(-x)); }
__device__ __forceinline__ float lrelu_(float x) { return x >= 0.f ? x : 0.01f * x; }
__device__ __forceinline__ u16 f2bf(float f) {
    u32 u = __float_as_uint(f);
    u += 0x7fffu + ((u >> 16) & 1u);
    return (u16)(u >> 16);
}
__device__ __forceinline__ float bf2f(u16 h) { return __uint_as_float(((u32)h) << 16); }
__device__ __forceinline__ u32 pk2(float a, float b) { return (u32)f2bf(a) | ((u32)f2bf(b) << 16); }

// ======== fused weight transpose (16 jobs in one launch) ========
struct WJob { const float* src; unsigned long dstOff; int OC, rowOff, IC, ICP, NT; unsigned long cum; };
struct WJobs { WJob j[16]; long total; };

__global__ __launch_bounds__(256) void k_wt_all(WJobs J, u16* __restrict__ base)
{
    long i = (long)blockIdx.x * 256 + threadIdx.x;
    if (i >= J.total) return;
    int jb = 0;
    #pragma unroll
    for (int k = 1; k < 16; ++k) if (i >= (long)J.j[k].cum) jb = k;
    WJob w = J.j[jb];
    long local = i - (long)w.cum;
    int c = (int)(local % w.ICP);
    int t = (int)((local / w.ICP) % w.NT);
    int o = (int)(local / ((long)w.ICP * w.NT));
    float val = (c < w.IC) ? w.src[((long)o * w.IC + c) * w.NT + t] : 0.f;
    base[w.dstOff + ((long)(w.rowOff + o) * w.NT + t) * w.ICP + c] = f2bf(val);
}

__global__ __launch_bounds__(256) void k_wt_dq(const float* __restrict__ w, u16* __restrict__ dst)
{
    int i = blockIdx.x * 256 + threadIdx.x;
    if (i >= 32768) return;
    int c = i & 63; int t = (i >> 6) & 3; int o = (i >> 8) & 31; int q = i >> 13;
    int ry = q >> 1, rx = q & 1, ta = t >> 1, tb = t & 1;
    int ky = ry + 2 * ta, kx = rx + 2 * tb;
    float val = w[(((long)o * 64 + c) * 4 + ky) * 4 + kx];
    dst[(long)q * 8192 + o * 256 + t * 64 + c] = f2bf(val);
}

__global__ __launch_bounds__(256) void k_wt5(const float* __restrict__ w, float* __restrict__ wt)
{
    int i = blockIdx.x * 256 + threadIdx.x;
    if (i >= 288) return;
    int t = i % 9, c = i / 9;
    wt[t * 32 + c] = w[c * 9 + t];
}

__global__ void k_catb(const float* __restrict__ a, const float* __restrict__ b, float* __restrict__ d)
{
    int i = threadIdx.x;
    if (i < 128) d[i] = a[i];
    else if (i < 256) d[i] = b[i - 128];
}

// ======== elementwise / prep kernels (channel-split for occupancy) ========
__global__ __launch_bounds__(256) void k_prep_f1(const float* __restrict__ fmap1, u16* __restrict__ f1bf)
{
    int gid = blockIdx.x * 256 + threadIdx.x;
    if (gid >= 24576) return;
    int idx = gid >> 1, half = gid & 1;
    int b = idx / HWW, p = idx % HWW;
    const float* fb = fmap1 + (long)b * 32 * HWW + p + (long)(half * 16) * HWW;
    u32 pk[8];
    #pragma unroll
    for (int c2 = 0; c2 < 8; ++c2)
        pk[c2] = pk2(fb[(long)(2 * c2) * HWW], fb[(long)(2 * c2 + 1) * HWW]);
    u16* op = f1bf + ((long)idx << 5) + half * 16;
    ((uint4*)op)[0] = make_uint4(pk[0], pk[1], pk[2], pk[3]);
    ((uint4*)op)[1] = make_uint4(pk[4], pk[5], pk[6], pk[7]);
}

__global__ __launch_bounds__(256) void k_warp(const float* __restrict__ fmap2, const float* __restrict__ flow,
                                              u16* __restrict__ f2wbf, float* __restrict__ cs)
{
    int gid = blockIdx.x * 256 + threadIdx.x;
    if (gid >= 24576) return;
    int idx = gid >> 1, half = gid & 1;
    int b = idx / HWW, p = idx % HWW, y = p / 96, x = p % 96;
    float u = flow[(b * 2 + 0) * HWW + p], v = flow[(b * 2 + 1) * HWW + p];
    float fx = (float)x + u, fy = (float)y + v;
    float fx0 = floorf(fx), fy0 = floorf(fy);
    float wx = fx - fx0, wy = fy - fy0;
    int x0 = (int)fx0, y0i = (int)fy0, x1 = x0 + 1, y1 = y0i + 1;
    bool vx0 = x0 >= 0 && x0 < 96, vx1 = x1 >= 0 && x1 < 96;
    bool vy0 = y0i >= 0 && y0i < 64, vy1 = y1 >= 0 && y1 < 64;
    float m00 = (vy0 && vx0) ? (1.f - wy) * (1.f - wx) : 0.f;
    float m01 = (vy0 && vx1) ? (1.f - wy) * wx : 0.f;
    float m10 = (vy1 && vx0) ? wy * (1.f - wx) : 0.f;
    float m11 = (vy1 && vx1) ? wy * wx : 0.f;
    int cx0 = min(max(x0, 0), 95), cx1 = min(max(x1, 0), 95);
    int cy0 = min(max(y0i, 0), 63), cy1 = min(max(y1, 0), 63);
    int i00 = cy0 * 96 + cx0, i01 = cy0 * 96 + cx1, i10 = cy1 * 96 + cx0, i11 = cy1 * 96 + cx1;
    const float* fb = fmap2 + (long)b * 32 * HWW + (long)(half * 16) * HWW;
    float s = 0.f; u32 pk[8];
    #pragma unroll
    for (int c2 = 0; c2 < 8; ++c2) {
        const float* fa = fb + (long)(2 * c2) * HWW;
        const float* fc = fb + (long)(2 * c2 + 1) * HWW;
        float g0 = m00 * fa[i00] + m01 * fa[i01] + m10 * fa[i10] + m11 * fa[i11];
        float g1 = m00 * fc[i00] + m01 * fc[i01] + m10 * fc[i10] + m11 * fc[i11];
        s += g0 + g1;
        pk[c2] = pk2(g0, g1);
    }
    u16* op = f2wbf + ((long)idx << 5) + half * 16;
    ((uint4*)op)[0] = make_uint4(pk[0], pk[1], pk[2], pk[3]);
    ((uint4*)op)[1] = make_uint4(pk[4], pk[5], pk[6], pk[7]);
    float stot = s + __shfl_xor(s, 1);
    if (half == 0) cs[idx] = stot;
}

// ======== MFMA implicit GEMM (unchanged core) ========
template<int BN, int MODE, int KH, int KW, int PH, int PW, int STRIDE, int ACT, int OUTF32>
__global__ __launch_bounds__(256) void k_gemm(
    const u16* __restrict__ A0, const u16* __restrict__ A1,
    const float* __restrict__ csm, const u16* __restrict__ Wb,
    const float* __restrict__ bias,
    u16* __restrict__ outb, u16* __restrict__ outb2, float* __restrict__ outf,
    int IH, int IW, int OH, int OW, int ICP, int NKT, int OC, int ldc, int coff, int nOff)
{
    constexpr int WAVES_M = (BN == 128) ? 2 : 4;
    constexpr int WTM = 128 / WAVES_M;
    constexpr int WTN = (BN == 128) ? 64 : BN;
    constexpr int MF = WTM / 16;
    constexpr int NF = WTN / 16;
    __shared__ u16 As[128 * 40];
    __shared__ u16 Bs[BN * 40];
    int tid = threadIdx.x;
    int mrow = tid >> 1;
    int khOff = (tid & 1) << 4;
    long gmS = (long)blockIdx.x * 128 + mrow;
    int nImg, y0, x0, bImg = 0, diS = 0, djS = 0, ryz = 0, rxz = 0;
    {
        int ohw = (MODE == 1) ? 6144 : ((MODE == 2) ? 1536 : OH * OW);
        int ow = (MODE == 1) ? 96 : ((MODE == 2) ? 48 : OW);
        nImg = (int)(gmS / ohw);
        int rem = (int)(gmS - (long)nImg * ohw);
        y0 = rem / ow; x0 = rem - y0 * ow;
        if (MODE == 1) {
            int n = nOff + nImg;
            bImg = n / 49; int kd = n - bImg * 49; diS = kd / 7 - 3; djS = kd % 7 - 3;
        }
        if (MODE == 2) { ryz = blockIdx.z >> 1; rxz = blockIdx.z & 1; }
    }
    const u16* WbZ = Wb;
    if (MODE == 2) WbZ += (long)blockIdx.z * 32 * 256;
    int n0 = blockIdx.y * BN;
    int lane = tid & 63, wid = tid >> 6;
    int wm = (BN == 128) ? (wid >> 1) : wid;
    int wn = (BN == 128) ? (wid & 1) : 0;
    int fr = lane & 15, fg = lane >> 4;
    f32x4 acc[MF][NF];
    #pragma unroll
    for (int i = 0; i < MF; ++i)
        #pragma unroll
        for (int j = 0; j < NF; ++j)
            acc[i][j] = (f32x4){0.f, 0.f, 0.f, 0.f};
    const int KTC = ICP >> 5;
    for (int kt = 0; kt < NKT; ++kt) {
        uint4 va0 = {0u,0u,0u,0u}, va1 = {0u,0u,0u,0u};
        if (MODE == 0) {
            int t = kt / KTC; int c0 = (kt - t * KTC) << 5;
            int dy = t / KW - PH, dx = t - (t / KW) * KW - PW;
            int iy = y0 * STRIDE + dy, ix = x0 * STRIDE + dx;
            if (iy >= 0 && iy < IH && ix >= 0 && ix < IW) {
                const u16* sp = A0 + ((long)(nImg * IH + iy) * IW + ix) * ICP + c0 + khOff;
                va0 = *(const uint4*)sp; va1 = *(const uint4*)(sp + 8);
            }
        } else if (MODE == 1) {
            int t = kt >> 1, half = kt & 1;
            int dy = t / 3 - 1, dx = t % 3 - 1;
            int yy = y0 + dy, xx = x0 + dx, ys = yy + djS, xs = xx + diS;
            if (yy >= 0 && yy < 64 && xx >= 0 && xx < 96 && ys >= 0 && ys < 64 && xs >= 0 && xs < 96) {
                if (csm[bImg * HWW + ys * 96 + xs] != 0.f) {
                    const u16* sp = half ? (A1 + (((long)bImg * HWW + ys * 96 + xs) << 5) + khOff)
                                         : (A0 + (((long)bImg * HWW + yy * 96 + xx) << 5) + khOff);
                    va0 = *(const uint4*)sp; va1 = *(const uint4*)(sp + 8);
                }
            }
        } else {
            int t = kt >> 1, c0 = (kt & 1) << 5;
            int ta = t >> 1, tb = t & 1;
            int iy = y0 + ryz + ta - 1, ix = x0 + rxz + tb - 1;
            if (iy >= 0 && iy < 32 && ix >= 0 && ix < 48) {
                const u16* sp = A0 + (((long)(nImg * 32 + iy) * 48 + ix) << 6) + c0 + khOff;
                va0 = *(const uint4*)sp; va1 = *(const uint4*)(sp + 8);
            }
        }
        *(uint4*)&As[mrow * 40 + khOff] = va0;
        *(uint4*)&As[mrow * 40 + khOff + 8] = va1;
        if (tid < 2 * BN) {
            int brow = tid >> 1; int ko = (tid & 1) << 4;
            const u16* wp = WbZ + (long)(n0 + brow) * (NKT * 32) + kt * 32 + ko;
            *(uint4*)&Bs[brow * 40 + ko] = *(const uint4*)wp;
            *(uint4*)&Bs[brow * 40 + ko + 8] = *(const uint4*)(wp + 8);
        }
        __syncthreads();
        bf16x8 af[MF], bfv[NF];
        #pragma unroll
        for (int i = 0; i < MF; ++i)
            af[i] = *(const bf16x8*)&As[(wm * WTM + i * 16 + fr) * 40 + fg * 8];
        #pragma unroll
        for (int j = 0; j < NF; ++j)
            bfv[j] = *(const bf16x8*)&Bs[(wn * WTN + j * 16 + fr) * 40 + fg * 8];
        #pragma unroll
        for (int i = 0; i < MF; ++i)
            #pragma unroll
            for (int j = 0; j < NF; ++j)
                acc[i][j] = __builtin_amdgcn_mfma_f32_16x16x32_bf16(af[i], bfv[j], acc[i][j], 0, 0, 0);
        __syncthreads();
    }
    // epilogue
    #pragma unroll
    for (int i = 0; i < MF; ++i) {
        #pragma unroll
        for (int j = 0; j < NF; ++j) {
            int nn = n0 + wn * WTN + j * 16 + fr;
            if (nn >= OC) continue;
            #pragma unroll
            for (int rr = 0; rr < 4; ++rr) {
                int mloc = wm * WTM + i * 16 + fg * 4 + rr;
                long gm = (long)blockIdx.x * 128 + mloc;
                float v = acc[i][j][rr] + bias[nn];
                if (ACT == 1) v = fmaxf(v, 0.f);
                else if (ACT == 2) v = lrelu_(v);
                if (OUTF32) {
                    outf[gm * ldc + coff + nn] = v;
                } else if (MODE == 2) {
                    int nI = (int)(gm / 1536); int rq = (int)(gm - (long)nI * 1536);
                    int Y = rq / 48, X = rq - (rq / 48) * 48;
                    long di = (((long)nI * 64 + 2 * Y + ryz) * 96 + (2 * X + rxz)) * 32 + nn;
                    outb[di] = f2bf(v);
                } else {
                    long di = gm * ldc + coff + nn;
                    u16 hv = f2bf(v);
                    outb[di] = hv;
                    if (outb2) outb2[di] = hv;
                }
            }
        }
    }
}

// ======== conv5 (32->1, 3x3) scalar over NHWC bf16 -> cvolT [b][p][64] bf16 ========
__global__ __launch_bounds__(256) void k_conv5n(const u16* __restrict__ x5, const float* __restrict__ w5t,
                                                const float* __restrict__ b5, u16* __restrict__ cvolT,
                                                int N, int n0)
{
    int idx = blockIdx.x * 256 + threadIdx.x;
    if (idx >= N * HWW) return;
    int nl = idx / HWW, p = idx % HWW, y = p / 96, x = p % 96;
    float acc = b5[0];
    #pragma unroll
    for (int t = 0; t < 9; ++t) {
        int iy = y + t / 3 - 1, ix = x + t % 3 - 1;
        if (iy < 0 || iy >= 64 || ix < 0 || ix >= 96) continue;
        const u16* sp = x5 + (((long)nl * HWW + iy * 96 + ix) << 5);
        const float* wt_ = w5t + t * 32;
        #pragma unroll
        for (int c8 = 0; c8 < 4; ++c8) {
            uint4 v = *(const uint4*)(sp + c8 * 8);
            acc = fmaf(bf2f((u16)(v.x & 0xffffu)), wt_[c8 * 8 + 0], acc);
            acc = fmaf(bf2f((u16)(v.x >> 16)),     wt_[c8 * 8 + 1], acc);
            acc = fmaf(bf2f((u16)(v.y & 0xffffu)), wt_[c8 * 8 + 2], acc);
            acc = fmaf(bf2f((u16)(v.y >> 16)),     wt_[c8 * 8 + 3], acc);
            acc = fmaf(bf2f((u16)(v.z & 0xffffu)), wt_[c8 * 8 + 4], acc);
            acc = fmaf(bf2f((u16)(v.z >> 16)),     wt_[c8 * 8 + 5], acc);
            acc = fmaf(bf2f((u16)(v.w & 0xffffu)), wt_[c8 * 8 + 6], acc);
            acc = fmaf(bf2f((u16)(v.w >> 16)),     wt_[c8 * 8 + 7], acc);
        }
    }
    int n = n0 + nl;
    int b = n / 49, k = n - b * 49;
    cvolT[((long)b * HWW + p) * 64 + k] = f2bf(acc);
}

// ======== mein ch 49..95 (fmap1, flow, zero-pad); 6-way channel split ========
__global__ __launch_bounds__(256) void k_me_tail(const float* __restrict__ fmap1, const float* __restrict__ flow,
                                                 u16* __restrict__ mein)
{
    int gid = blockIdx.x * 256 + threadIdx.x;
    if (gid >= 73728) return;
    int j = gid / 12288, idx = gid - j * 12288;
    int b = idx / HWW, p = idx % HWW;
    int c0 = 49 + j * 8;
    u16* mp = mein + (long)idx * 96;
    #pragma unroll
    for (int q = 0; q < 8; ++q) {
        int c = c0 + q;
        if (c >= 96) break;
        float v;
        if (c < 81) v = fmap1[((long)(b * 32 + (c - 49))) * HWW + p];
        else if (c == 81) v = flow[(b * 2 + 0) * HWW + p];
        else if (c == 82) v = flow[(b * 2 + 1) * HWW + p];
        else v = 0.f;
        mp[c] = f2bf(v);
    }
}

// ======== set hx head from h (NCHW f32) + hst + flow tails; 4-way channel split ========
__global__ __launch_bounds__(256) void k_set_head(const float* __restrict__ h, const float* __restrict__ flow,
                                                  float* __restrict__ hst, u16* __restrict__ hx,
                                                  u16* __restrict__ hx2)
{
    int gid = blockIdx.x * 256 + threadIdx.x;
    if (gid >= 49152) return;
    int cq = gid / 12288, idx = gid - cq * 12288;
    int b = idx / HWW, p = idx % HWW;
    int c0 = cq * 32;
    const float* hp = h + (long)b * 128 * HWW + p;
    float* hs = hst + (long)idx * 128;
    u16* hxp = hx + (long)idx * 224;
    #pragma unroll
    for (int c = c0; c < c0 + 32; c += 8) {
        float v[8];
        #pragma unroll
        for (int q = 0; q < 8; ++q) v[q] = hp[(long)(c + q) * HWW];
        *(float4*)&hs[c] = make_float4(v[0], v[1], v[2], v[3]);
        *(float4*)&hs[c + 4] = make_float4(v[4], v[5], v[6], v[7]);
        uint4 pk = make_uint4(pk2(v[0], v[1]), pk2(v[2], v[3]), pk2(v[4], v[5]), pk2(v[6], v[7]));
        *(uint4*)&hxp[c] = pk;
    }
    if (cq == 0) {
        u16 uu = f2bf(flow[(b * 2 + 0) * HWW + p]);
        u16 vv = f2bf(flow[(b * 2 + 1) * HWW + p]);
        long o = (long)idx * 224;
        hx[o + 222] = uu; hx[o + 223] = vv;
        hx2[o + 222] = uu; hx2[o + 223] = vv;
    }
}

// ======== GRU post z/r; 4-way channel split ========
__global__ __launch_bounds__(256) void k_post_zr(const float* __restrict__ azr, const float* __restrict__ hst,
                                                 float* __restrict__ z, u16* __restrict__ hx2)
{
    int gid = blockIdx.x * 256 + threadIdx.x;
    if (gid >= 49152) return;
    int cq = gid / 12288, idx = gid - cq * 12288;
    int c0 = cq * 32;
    const float* ap = azr + (long)idx * 256;
    const float* hs = hst + (long)idx * 128;
    float* zp = z + (long)idx * 128;
    u16* xp = hx2 + (long)idx * 224;
    #pragma unroll
    for (int c = c0; c < c0 + 32; c += 8) {
        float4 a0 = *(const float4*)&ap[c], a1 = *(const float4*)&ap[c + 4];
        float4 r0 = *(const float4*)&ap[128 + c], r1 = *(const float4*)&ap[128 + c + 4];
        float4 h0 = *(const float4*)&hs[c], h1v = *(const float4*)&hs[c + 4];
        float z0 = sigmoidf_(a0.x), z1 = sigmoidf_(a0.y), z2 = sigmoidf_(a0.z), z3 = sigmoidf_(a0.w);
        float z4 = sigmoidf_(a1.x), z5 = sigmoidf_(a1.y), z6 = sigmoidf_(a1.z), z7 = sigmoidf_(a1.w);
        *(float4*)&zp[c] = make_float4(z0, z1, z2, z3);
        *(float4*)&zp[c + 4] = make_float4(z4, z5, z6, z7);
        float rh0 = sigmoidf_(r0.x) * h0.x, rh1 = sigmoidf_(r0.y) * h0.y;
        float rh2 = sigmoidf_(r0.z) * h0.z, rh3 = sigmoidf_(r0.w) * h0.w;
        float rh4 = sigmoidf_(r1.x) * h1v.x, rh5 = sigmoidf_(r1.y) * h1v.y;
        float rh6 = sigmoidf_(r1.z) * h1v.z, rh7 = sigmoidf_(r1.w) * h1v.w;
        uint4 pk = make_uint4(pk2(rh0, rh1), pk2(rh2, rh3), pk2(rh4, rh5), pk2(rh6, rh7));
        *(uint4*)&xp[c] = pk;
    }
}

// ======== GRU post q; 4-way channel split ========
template<int FIN>
__global__ __launch_bounds__(256) void k_post_q(const float* __restrict__ aq, const float* __restrict__ z,
                                                const float* __restrict__ hst, float* __restrict__ h1f,
                                                u16* __restrict__ hxdst, float* __restrict__ outH)
{
    int gid = blockIdx.x * 256 + threadIdx.x;
    if (gid >= 49152) return;
    int cq = gid / 12288, idx = gid - cq * 12288;
    int b = idx / HWW, p = idx % HWW;
    int c0 = cq * 32;
    const float* ap = aq + (long)idx * 128;
    const float* zp = z + (long)idx * 128;
    const float* hs = hst + (long)idx * 128;
    #pragma unroll
    for (int c = c0; c < c0 + 32; c += 8) {
        float hn[8];
        #pragma unroll
        for (int q = 0; q < 8; ++q) {
            float qq = tanhf(ap[c + q]);
            float zv = zp[c + q];
            hn[q] = (1.f - zv) * hs[c + q] + zv * qq;
        }
        uint4 pk = make_uint4(pk2(hn[0], hn[1]), pk2(hn[2], hn[3]), pk2(hn[4], hn[5]), pk2(hn[6], hn[7]));
        if (FIN == 0) {
            *(float4*)&h1f[(long)idx * 128 + c] = make_float4(hn[0], hn[1], hn[2], hn[3]);
            *(float4*)&h1f[(long)idx * 128 + c + 4] = make_float4(hn[4], hn[5], hn[6], hn[7]);
            *(uint4*)&hxdst[(long)idx * 224 + c] = pk;
        } else {
            #pragma unroll
            for (int q = 0; q < 8; ++q)
                outH[((long)(b * 128 + c + q)) * HWW + p] = hn[q];
            *(uint4*)&hxdst[(long)idx * 128 + c] = pk;
        }
    }
}

// ======== softmax + expectation + flow add (logits from fh2 GEMM, lrelu pre-applied) ========
__global__ __launch_bounds__(256) void k_soft(const float* __restrict__ s2, const float* __restrict__ flow,
                                              float* __restrict__ outFlow)
{
    int idx = blockIdx.x * 256 + threadIdx.x;
    if (idx >= 12288) return;
    int b = idx / HWW, p = idx % HWW;
    const float* sp = s2 + (long)idx * 64;
    float lg[49];
    #pragma unroll
    for (int k = 0; k < 48; k += 4) {
        float4 v = *(const float4*)&sp[k];
        lg[k] = v.x; lg[k + 1] = v.y; lg[k + 2] = v.z; lg[k + 3] = v.w;
    }
    lg[48] = sp[48];
    float m = -1e30f;
    #pragma unroll
    for (int k = 0; k < 49; ++k) m = fmaxf(m, lg[k]);
    float s = 0.f, a0 = 0.f, a1 = 0.f;
    #pragma unroll
    for (int k = 0; k < 49; ++k) {
        float e = expf(lg[k] - m);
        s += e;
        a0 += e * (float)(k / 7 - 3);
        a1 += e * (float)(k % 7 - 3);
    }
    float inv = 1.f / s;
    outFlow[(long)(b * 2 + 0) * HWW + p] = flow[(long)(b * 2 + 0) * HWW + p] + a0 * inv;
    outFlow[(long)(b * 2 + 1) * HWW + p] = flow[(long)(b * 2 + 1) * HWW + p] + a1 * inv;
}

extern "C" void kernel_launch(void* const* d_in, const int* in_sizes, int n_in,
                              void* d_out, int out_size, void* d_ws, size_t ws_size,
                              hipStream_t stream)
{
    const float* fmap1 = (const float*)d_in[0];
    const float* fmap2 = (const float*)d_in[1];
    const float* h     = (const float*)d_in[2];
    const float* flow  = (const float*)d_in[3];
    int pb = (in_sizes[4] == 1) ? 5 : 4;
    const float* mn_w1 = (const float*)d_in[pb + 0];
    const float* mn_b1 = (const float*)d_in[pb + 1];
    const float* mn_w2 = (const float*)d_in[pb + 2];
    const float* mn_b2 = (const float*)d_in[pb + 3];
    const float* mn_w3 = (const float*)d_in[pb + 4];
    const float* mn_b3 = (const float*)d_in[pb + 5];
    const float* mn_w4 = (const float*)d_in[pb + 6];
    const float* mn_b4 = (const float*)d_in[pb + 7];
    const float* mn_wd = (const float*)d_in[pb + 8];
    const float* mn_bd = (const float*)d_in[pb + 9];
    const float* mn_w5 = (const float*)d_in[pb + 10];
    const float* mn_b5 = (const float*)d_in[pb + 11];
    const float* dap_w = (const float*)d_in[pb + 12];
    const float* dap_b = (const float*)d_in[pb + 13];
    const float* me_w1 = (const float*)d_in[pb + 14];
    const float* me_b1 = (const float*)d_in[pb + 15];
    const float* me_w2 = (const float*)d_in[pb + 16];
    const float* me_b2 = (const float*)d_in[pb + 17];
    const float* me_w3 = (const float*)d_in[pb + 18];
    const float* me_b3 = (const float*)d_in[pb + 19];
    const float* gz1_w = (const float*)d_in[pb + 20];
    const float* gz1_b = (const float*)d_in[pb + 21];
    const float* gr1_w = (const float*)d_in[pb + 22];
    const float* gr1_b = (const float*)d_in[pb + 23];
    const float* gq1_w = (const float*)d_in[pb + 24];
    const float* gq1_b = (const float*)d_in[pb + 25];
    const float* gz2_w = (const float*)d_in[pb + 26];
    const float* gz2_b = (const float*)d_in[pb + 27];
    const float* gr2_w = (const float*)d_in[pb + 28];
    const float* gr2_b = (const float*)d_in[pb + 29];
    const float* gq2_w = (const float*)d_in[pb + 30];
    const float* gq2_b = (const float*)d_in[pb + 31];
    const float* fh_w1 = (const float*)d_in[pb + 32];
    const float* fh_b1 = (const float*)d_in[pb + 33];
    const float* fh_w2 = (const float*)d_in[pb + 34];
    const float* fh_b2 = (const float*)d_in[pb + 35];

    char* wsB = (char*)d_ws;
    size_t off = 0;
    auto alc = [&](size_t bytes) { size_t o = off; off = (off + bytes + 255) & ~(size_t)255; return o; };

    // ---- weight arena (memset to 0 first) ----
    size_t o_wc1  = alc(128 * 576 * 2);
    size_t o_wc2  = alc(128 * 864 * 2);
    size_t o_wc3  = alc((size_t)128 * 1152 * 2);
    size_t o_wc4  = alc((size_t)64 * 1152 * 2);
    size_t o_wdq  = alc(32768 * 2);
    size_t o_wme1 = alc(128 * 864 * 2);
    size_t o_wme2 = alc((size_t)128 * 1152 * 2);
    size_t o_wme3 = alc((size_t)128 * 1152 * 2);
    size_t o_wzr1 = alc((size_t)256 * 1120 * 2);
    size_t o_wq1  = alc((size_t)128 * 1120 * 2);
    size_t o_wzr2 = alc((size_t)256 * 1120 * 2);
    size_t o_wq2  = alc((size_t)128 * 1120 * 2);
    size_t o_wfh1 = alc(256 * 128 * 2);
    size_t o_wfh2 = alc(64 * 256 * 2);
    size_t o_wdapb= alc(64 * 64 * 2);
    size_t o_w5t  = alc(288 * 4);
    size_t o_bzr1 = alc(256 * 4);
    size_t o_bzr2 = alc(256 * 4);
    size_t wArenaBytes = off;

    // ---- persistent activations ----
    size_t o_f1bf = alc((size_t)12288 * 32 * 2);
    size_t o_f2wb = alc((size_t)12288 * 32 * 2);
    size_t o_cs   = alc(12288 * 4);
    size_t o_cvolT= alc((size_t)12288 * 64 * 2);

    // ---- shared region: phase-A x-scratch (CH=49) overlaid with phase-B buffers ----
    const int CH = 49;
    size_t sharedBase = off;
    size_t offA = sharedBase;
    auto alcA = [&](size_t bytes) { size_t o = offA; offA = (offA + bytes + 255) & ~(size_t)255; return o; };
    size_t o_x1 = alcA((size_t)CH * 6144 * 96 * 2);
    size_t o_x2 = alcA((size_t)CH * 1536 * 128 * 2);
    size_t o_x3 = alcA((size_t)CH * 1536 * 128 * 2);
    size_t o_x4 = alcA((size_t)CH * 1536 * 64 * 2);
    size_t o_x5 = alcA((size_t)CH * 6144 * 32 * 2);
    size_t offB2 = sharedBase;
    auto alcB = [&](size_t bytes) { size_t o = offB2; offB2 = (offB2 + bytes + 255) & ~(size_t)255; return o; };
    size_t o_mein = alcB((size_t)12288 * 96 * 2);
    size_t o_m1   = alcB((size_t)12288 * 128 * 2);
    size_t o_m2   = alcB((size_t)12288 * 128 * 2);
    size_t o_hx   = alcB((size_t)12288 * 224 * 2);
    size_t o_hx2  = alcB((size_t)12288 * 224 * 2);
    size_t o_h2bf = alcB((size_t)12288 * 128 * 2);
    size_t o_s1b  = alcB((size_t)12288 * 256 * 2);
    size_t o_hst  = alcB((size_t)12288 * 128 * 4);
    size_t o_h1f  = alcB((size_t)12288 * 128 * 4);
    size_t o_zf   = alcB((size_t)12288 * 128 * 4);
    size_t o_azr  = alcB((size_t)12288 * 256 * 4);
    size_t o_aqf  = alcB((size_t)12288 * 128 * 4);
    size_t o_s2   = alcB((size_t)12288 * 64 * 4);

    u16* wbase = (u16*)wsB;
    u16* wdq  = (u16*)(wsB + o_wdq);
    float* w5t = (float*)(wsB + o_w5t);
    float* bzr1 = (float*)(wsB + o_bzr1);
    float* bzr2 = (float*)(wsB + o_bzr2);
    u16* wc1  = (u16*)(wsB + o_wc1);   u16* wc2  = (u16*)(wsB + o_wc2);
    u16* wc3  = (u16*)(wsB + o_wc3);   u16* wc4  = (u16*)(wsB + o_wc4);
    u16* wme1 = (u16*)(wsB + o_wme1);  u16* wme2 = (u16*)(wsB + o_wme2);
    u16* wme3 = (u16*)(wsB + o_wme3);
    u16* wzr1 = (u16*)(wsB + o_wzr1);  u16* wq1  = (u16*)(wsB + o_wq1);
    u16* wzr2 = (u16*)(wsB + o_wzr2);  u16* wq2  = (u16*)(wsB + o_wq2);
    u16* wfh1 = (u16*)(wsB + o_wfh1);  u16* wfh2 = (u16*)(wsB + o_wfh2);
    u16* wdapb= (u16*)(wsB + o_wdapb);

    u16* f1bf = (u16*)(wsB + o_f1bf);  u16* f2wb = (u16*)(wsB + o_f2wb);
    float* cs = (float*)(wsB + o_cs);
    u16* cvolT = (u16*)(wsB + o_cvolT);
    u16* x1 = (u16*)(wsB + o_x1); u16* x2 = (u16*)(wsB + o_x2); u16* x3 = (u16*)(wsB + o_x3);
    u16* x4 = (u16*)(wsB + o_x4); u16* x5 = (u16*)(wsB + o_x5);
    u16* mein = (u16*)(wsB + o_mein);
    u16* m1 = (u16*)(wsB + o_m1); u16* m2 = (u16*)(wsB + o_m2);
    u16* hx = (u16*)(wsB + o_hx); u16* hx2 = (u16*)(wsB + o_hx2);
    u16* h2bf = (u16*)(wsB + o_h2bf);  u16* s1b = (u16*)(wsB + o_s1b);
    float* hst = (float*)(wsB + o_hst); float* h1f = (float*)(wsB + o_h1f);
    float* zf = (float*)(wsB + o_zf); float* azr = (float*)(wsB + o_azr);
    float* aqf = (float*)(wsB + o_aqf); float* s2 = (float*)(wsB + o_s2);

    float* outH = (float*)d_out;
    float* outFlow = outH + (long)2 * 128 * HWW;

    auto nb = [](long total, int bs) { return (unsigned)((total + bs - 1) / bs); };

    // ---- weight preps ----
    hipMemsetAsync(wsB, 0, wArenaBytes, stream);
    hipMemsetAsync(wsB + o_cvolT, 0, (size_t)12288 * 64 * 2, stream);

    WJobs J;
    {
        auto mk = [](const float* src, size_t dstOffBytes, int OC, int rowOff, int IC, int ICP, int NT) {
            WJob w; w.src = src; w.dstOff = dstOffBytes / 2; w.OC = OC; w.rowOff = rowOff;
            w.IC = IC; w.ICP = ICP; w.NT = NT; w.cum = 0; return w;
        };
        J.j[0]  = mk(mn_w1, o_wc1, 96, 0, 64, 64, 9);
        J.j[1]  = mk(mn_w2, o_wc2, 128, 0, 96, 96, 9);
        J.j[2]  = mk(mn_w3, o_wc3, 128, 0, 128, 128, 9);
        J.j[3]  = mk(mn_w4, o_wc4, 64, 0, 128, 128, 9);
        J.j[4]  = mk(me_w1, o_wme1, 128, 0, 83, 96, 9);
        J.j[5]  = mk(me_w2, o_wme2, 128, 0, 128, 128, 9);
        J.j[6]  = mk(me_w3, o_wme3, 94, 0, 128, 128, 9);
        J.j[7]  = mk(gz1_w, o_wzr1, 128, 0, 224, 224, 5);
        J.j[8]  = mk(gr1_w, o_wzr1, 128, 128, 224, 224, 5);
        J.j[9]  = mk(gq1_w, o_wq1, 128, 0, 224, 224, 5);
        J.j[10] = mk(gz2_w, o_wzr2, 128, 0, 224, 224, 5);
        J.j[11] = mk(gr2_w, o_wzr2, 128, 128, 224, 224, 5);
        J.j[12] = mk(gq2_w, o_wq2, 128, 0, 224, 224, 5);
        J.j[13] = mk(fh_w1, o_wfh1, 256, 0, 128, 128, 1);
        J.j[14] = mk(fh_w2, o_wfh2, 49, 0, 256, 256, 1);
        J.j[15] = mk(dap_w, o_wdapb, 49, 0, 49, 64, 1);
        long cum = 0;
        for (int k = 0; k < 16; ++k) {
            J.j[k].cum = cum;
            cum += (long)J.j[k].OC * J.j[k].NT * J.j[k].ICP;
        }
        J.total = cum;
    }
    k_wt_all<<<nb(J.total, 256), 256, 0, stream>>>(J, wbase);
    k_wt_dq<<<nb(32768, 256), 256, 0, stream>>>(mn_wd, wdq);
    k_wt5<<<2, 256, 0, stream>>>(mn_w5, w5t);
    k_catb<<<1, 256, 0, stream>>>(gz1_b, gr1_b, bzr1);
    k_catb<<<1, 256, 0, stream>>>(gz2_b, gr2_b, bzr2);

    // ---- input preps ----
    k_prep_f1<<<nb(24576, 256), 256, 0, stream>>>(fmap1, f1bf);
    k_warp<<<nb(24576, 256), 256, 0, stream>>>(fmap2, flow, f2wb, cs);

    // ---- matching net: 2 chunks of 49 displacement-batches ----
    for (int n0 = 0; n0 < 98; n0 += CH) {
        k_gemm<128,1,3,3,1,1,1,1,0><<<dim3(2352, 1), 256, 0, stream>>>(
            f1bf, f2wb, cs, wc1, mn_b1, x1, nullptr, nullptr, 64, 96, 64, 96, 32, 18, 96, 96, 0, n0);
        k_gemm<128,0,3,3,1,1,2,1,0><<<dim3(588, 1), 256, 0, stream>>>(
            x1, nullptr, nullptr, wc2, mn_b2, x2, nullptr, nullptr, 64, 96, 32, 48, 96, 27, 128, 128, 0, 0);
        k_gemm<128,0,3,3,1,1,1,1,0><<<dim3(588, 1), 256, 0, stream>>>(
            x2, nullptr, nullptr, wc3, mn_b3, x3, nullptr, nullptr, 32, 48, 32, 48, 128, 36, 128, 128, 0, 0);
        k_gemm<64,0,3,3,1,1,1,1,0><<<dim3(588, 1), 256, 0, stream>>>(
            x3, nullptr, nullptr, wc4, mn_b4, x4, nullptr, nullptr, 32, 48, 32, 48, 128, 36, 64, 64, 0, 0);
        k_gemm<32,2,4,4,2,2,1,1,0><<<dim3(588, 1, 4), 256, 0, stream>>>(
            x4, nullptr, nullptr, wdq, mn_bd, x5, nullptr, nullptr, 32, 48, 32, 48, 64, 8, 32, 32, 0, 0);
        k_conv5n<<<nb((long)CH * HWW, 256), 256, 0, stream>>>(x5, w5t, mn_b5, cvolT, CH, n0);
    }

    // ---- DAP (MFMA GEMM over 64-padded displacement channels) + me tail ----
    k_gemm<64,0,1,1,0,0,1,0,0><<<dim3(96, 1), 256, 0, stream>>>(
        cvolT, nullptr, nullptr, wdapb, dap_b, mein, nullptr, nullptr, 64, 96, 64, 96, 64, 2, 49, 96, 0, 0);
    k_me_tail<<<nb(73728, 256), 256, 0, stream>>>(fmap1, flow, mein);

    // ---- motion encoder ----
    k_gemm<128,0,3,3,1,1,1,2,0><<<dim3(96, 1), 256, 0, stream>>>(
        mein, nullptr, nullptr, wme1, me_b1, m1, nullptr, nullptr, 64, 96, 64, 96, 96, 27, 128, 128, 0, 0);
    k_gemm<128,0,3,3,1,1,1,2,0><<<dim3(96, 1), 256, 0, stream>>>(
        m1, nullptr, nullptr, wme2, me_b2, m2, nullptr, nullptr, 64, 96, 64, 96, 128, 36, 128, 128, 0, 0);
    k_gemm<128,0,3,3,1,1,1,0,0><<<dim3(96, 1), 256, 0, stream>>>(
        m2, nullptr, nullptr, wme3, me_b3, hx, hx2, nullptr, 64, 96, 64, 96, 128, 36, 94, 224, 128, 0);

    // ---- GRU 1 (horizontal 1x5) ----
    k_set_head<<<nb(49152, 256), 256, 0, stream>>>(h, flow, hst, hx, hx2);
    k_gemm<128,0,1,5,0,2,1,0,1><<<dim3(96, 2), 256, 0, stream>>>(
        hx, nullptr, nullptr, wzr1, bzr1, nullptr, nullptr, azr, 64, 96, 64, 96, 224, 35, 256, 256, 0, 0);
    k_post_zr<<<nb(49152, 256), 256, 0, stream>>>(azr, hst, zf, hx2);
    k_gemm<128,0,1,5,0,2,1,0,1><<<dim3(96, 1), 256, 0, stream>>>(
        hx2, nullptr, nullptr, wq1, gq1_b, nullptr, nullptr, aqf, 64, 96, 64, 96, 224, 35, 128, 128, 0, 0);
    k_post_q<0><<<nb(49152, 256), 256, 0, stream>>>(aqf, zf, hst, h1f, hx, nullptr);

    // ---- GRU 2 (vertical 5x1) ----
    k_gemm<128,0,5,1,2,0,1,0,1><<<dim3(96, 2), 256, 0, stream>>>(
        hx, nullptr, nullptr, wzr2, bzr2, nullptr, nullptr, azr, 64, 96, 64, 96, 224, 35, 256, 256, 0, 0);
    k_post_zr<<<nb(49152, 256), 256, 0, stream>>>(azr, h1f, zf, hx2);
    k_gemm<128,0,5,1,2,0,1,0,1><<<dim3(96, 1), 256, 0, stream>>>(
        hx2, nullptr, nullptr, wq2, gq2_b, nullptr, nullptr, aqf, 64, 96, 64, 96, 224, 35, 128, 128, 0, 0);
    k_post_q<1><<<nb(49152, 256), 256, 0, stream>>>(aqf, zf, h1f, nullptr, h2bf, outH);

    // ---- flow head (both layers as MFMA GEMM, then tiny softmax) ----
    k_gemm<128,0,1,1,0,0,1,2,0><<<dim3(96, 2), 256, 0, stream>>>(
        h2bf, nullptr, nullptr, wfh1, fh_b1, s1b, nullptr, nullptr, 64, 96, 64, 96, 128, 4, 256, 256, 0, 0);
    k_gemm<64,0,1,1,0,0,1,2,1><<<dim3(96, 1), 256, 0, stream>>>(
        s1b, nullptr, nullptr, wfh2, fh_b2, nullptr, nullptr, s2, 64, 96, 64, 96, 256, 8, 49, 64, 0, 0);
    k_soft<<<nb(12288, 256), 256, 0, stream>>>(s2, flow, outFlow);
}

// Round 7
// 798.681 us; speedup vs baseline: 48.3570x; 1.2237x over previous
//
#include <hip/hip_runtime.h>
#include <math.h>

typedef unsigned short u16;
typedef unsigned int u32;
typedef __attribute__((ext_vector_type(8))) short bf16x8;
typedef __attribute__((ext_vector_type(4))) float f32x4;

#define HWW 6144

__device__ __forceinline__ float sigmoidf_(float x) { return 1.f / (1.f + expf(-x)); }
__device__ __forceinline__ float lrelu_(float x) { return x >= 0.f ? x : 0.01f * x; }
__device__ __forceinline__ u16 f2bf(float f) {
    u32 u = __float_as_uint(f);
    u += 0x7fffu + ((u >> 16) & 1u);
    return (u16)(u >> 16);
}
__device__ __forceinline__ float bf2f(u16 h) { return __uint_as_float(((u32)h) << 16); }
__device__ __forceinline__ u32 pk2(float a, float b) { return (u32)f2bf(a) | ((u32)f2bf(b) << 16); }

// ======== fused weight transpose (16 jobs in one launch) ========
struct WJob { const float* src; unsigned long dstOff; int OC, rowOff, IC, ICP, NT; unsigned long cum; };
struct WJobs { WJob j[16]; long total; };

__global__ __launch_bounds__(256) void k_wt_all(WJobs J, u16* __restrict__ base)
{
    long i = (long)blockIdx.x * 256 + threadIdx.x;
    if (i >= J.total) return;
    int jb = 0;
    #pragma unroll
    for (int k = 1; k < 16; ++k) if (i >= (long)J.j[k].cum) jb = k;
    WJob w = J.j[jb];
    long local = i - (long)w.cum;
    int c = (int)(local % w.ICP);
    int t = (int)((local / w.ICP) % w.NT);
    int o = (int)(local / ((long)w.ICP * w.NT));
    float val = (c < w.IC) ? w.src[((long)o * w.IC + c) * w.NT + t] : 0.f;
    base[w.dstOff + ((long)(w.rowOff + o) * w.NT + t) * w.ICP + c] = f2bf(val);
}

__global__ __launch_bounds__(256) void k_wt_dq(const float* __restrict__ w, u16* __restrict__ dst)
{
    int i = blockIdx.x * 256 + threadIdx.x;
    if (i >= 32768) return;
    int c = i & 63; int t = (i >> 6) & 3; int o = (i >> 8) & 31; int q = i >> 13;
    int ry = q >> 1, rx = q & 1, ta = t >> 1, tb = t & 1;
    int ky = ry + 2 * ta, kx = rx + 2 * tb;
    float val = w[(((long)o * 64 + c) * 4 + ky) * 4 + kx];
    dst[(long)q * 8192 + o * 256 + t * 64 + c] = f2bf(val);
}

__global__ __launch_bounds__(256) void k_wt5(const float* __restrict__ w, float* __restrict__ wt)
{
    int i = blockIdx.x * 256 + threadIdx.x;
    if (i >= 288) return;
    int t = i % 9, c = i / 9;
    wt[t * 32 + c] = w[c * 9 + t];
}

__global__ void k_catb(const float* __restrict__ a, const float* __restrict__ b, float* __restrict__ d)
{
    int i = threadIdx.x;
    if (i < 128) d[i] = a[i];
    else if (i < 256) d[i] = b[i - 128];
}

// ======== elementwise / prep kernels ========
__global__ __launch_bounds__(256) void k_prep_f1(const float* __restrict__ fmap1, u16* __restrict__ f1bf)
{
    int gid = blockIdx.x * 256 + threadIdx.x;
    if (gid >= 24576) return;
    int idx = gid >> 1, half = gid & 1;
    int b = idx / HWW, p = idx % HWW;
    const float* fb = fmap1 + (long)b * 32 * HWW + p + (long)(half * 16) * HWW;
    u32 pk[8];
    #pragma unroll
    for (int c2 = 0; c2 < 8; ++c2)
        pk[c2] = pk2(fb[(long)(2 * c2) * HWW], fb[(long)(2 * c2 + 1) * HWW]);
    u16* op = f1bf + ((long)idx << 5) + half * 16;
    ((uint4*)op)[0] = make_uint4(pk[0], pk[1], pk[2], pk[3]);
    ((uint4*)op)[1] = make_uint4(pk[4], pk[5], pk[6], pk[7]);
}

__global__ __launch_bounds__(256) void k_warp(const float* __restrict__ fmap2, const float* __restrict__ flow,
                                              u16* __restrict__ f2wbf, float* __restrict__ cs)
{
    int gid = blockIdx.x * 256 + threadIdx.x;
    if (gid >= 24576) return;
    int idx = gid >> 1, half = gid & 1;
    int b = idx / HWW, p = idx % HWW, y = p / 96, x = p % 96;
    float u = flow[(b * 2 + 0) * HWW + p], v = flow[(b * 2 + 1) * HWW + p];
    float fx = (float)x + u, fy = (float)y + v;
    float fx0 = floorf(fx), fy0 = floorf(fy);
    float wx = fx - fx0, wy = fy - fy0;
    int x0 = (int)fx0, y0i = (int)fy0, x1 = x0 + 1, y1 = y0i + 1;
    bool vx0 = x0 >= 0 && x0 < 96, vx1 = x1 >= 0 && x1 < 96;
    bool vy0 = y0i >= 0 && y0i < 64, vy1 = y1 >= 0 && y1 < 64;
    float m00 = (vy0 && vx0) ? (1.f - wy) * (1.f - wx) : 0.f;
    float m01 = (vy0 && vx1) ? (1.f - wy) * wx : 0.f;
    float m10 = (vy1 && vx0) ? wy * (1.f - wx) : 0.f;
    float m11 = (vy1 && vx1) ? wy * wx : 0.f;
    int cx0 = min(max(x0, 0), 95), cx1 = min(max(x1, 0), 95);
    int cy0 = min(max(y0i, 0), 63), cy1 = min(max(y1, 0), 63);
    int i00 = cy0 * 96 + cx0, i01 = cy0 * 96 + cx1, i10 = cy1 * 96 + cx0, i11 = cy1 * 96 + cx1;
    const float* fb = fmap2 + (long)b * 32 * HWW + (long)(half * 16) * HWW;
    float s = 0.f; u32 pk[8];
    #pragma unroll
    for (int c2 = 0; c2 < 8; ++c2) {
        const float* fa = fb + (long)(2 * c2) * HWW;
        const float* fc = fb + (long)(2 * c2 + 1) * HWW;
        float g0 = m00 * fa[i00] + m01 * fa[i01] + m10 * fa[i10] + m11 * fa[i11];
        float g1 = m00 * fc[i00] + m01 * fc[i01] + m10 * fc[i10] + m11 * fc[i11];
        s += g0 + g1;
        pk[c2] = pk2(g0, g1);
    }
    u16* op = f2wbf + ((long)idx << 5) + half * 16;
    ((uint4*)op)[0] = make_uint4(pk[0], pk[1], pk[2], pk[3]);
    ((uint4*)op)[1] = make_uint4(pk[4], pk[5], pk[6], pk[7]);
    float stot = s + __shfl_xor(s, 1);
    if (half == 0) cs[idx] = stot;
}

// ======== MFMA implicit GEMM: compile-time dims, double-buffered LDS, 1 barrier/K-step ========
// MODE 0: standard conv NHWC bf16; MODE 1: conv1 fused mvol; MODE 2: deconv quadrant (blockIdx.z)
template<int BN, int MODE, int KH, int KW, int PH, int PW, int STRIDE, int ACT, int OUTF32,
         int IH, int IW, int OH, int OW, int ICP, int NKT>
__global__ __launch_bounds__(256) void k_gemm(
    const u16* __restrict__ A0, const u16* __restrict__ A1,
    const float* __restrict__ csm, const u16* __restrict__ Wb,
    const float* __restrict__ bias,
    u16* __restrict__ outb, u16* __restrict__ outb2, float* __restrict__ outf,
    int OC, int ldc, int coff, int nOff)
{
    constexpr int WAVES_M = (BN == 128) ? 2 : 4;
    constexpr int WTM = 128 / WAVES_M;
    constexpr int WTN = (BN == 128) ? 64 : BN;
    constexpr int MF = WTM / 16;
    constexpr int NF = WTN / 16;
    constexpr int LDR = 40;
    __shared__ u16 As[2][128 * LDR];
    __shared__ u16 Bs[2][BN * LDR];
    int tid = threadIdx.x;
    int mrow = tid >> 1;
    int khOff = (tid & 1) << 4;
    int gmS = blockIdx.x * 128 + mrow;

    constexpr int OHW = (MODE == 1) ? 6144 : ((MODE == 2) ? 1536 : OH * OW);
    constexpr int OWW = (MODE == 1) ? 96 : ((MODE == 2) ? 48 : OW);
    int nImg = gmS / OHW;
    int rem = gmS - nImg * OHW;
    int y0 = rem / OWW, x0 = rem - y0 * OWW;

    int ryz = 0, rxz = 0, diS = 0, djS = 0, bImgHWW = 0;
    u32 vmask = 0;
    const u16* Arow = A0;
    if (MODE == 0) {
        Arow = A0 + ((long)nImg * IH * IW + (long)y0 * STRIDE * IW + (long)x0 * STRIDE) * ICP + khOff;
    } else if (MODE == 1) {
        int n = nOff + nImg;
        int bImg = n / 49; int kd = n - bImg * 49;
        diS = kd / 7 - 3; djS = kd % 7 - 3;
        bImgHWW = bImg * HWW;
        #pragma unroll
        for (int t = 0; t < 9; ++t) {
            int dy = t / 3 - 1, dx = t % 3 - 1;
            int yy = y0 + dy, xx = x0 + dx, ys = yy + djS, xs = xx + diS;
            bool v = yy >= 0 && yy < 64 && xx >= 0 && xx < 96 && ys >= 0 && ys < 64 && xs >= 0 && xs < 96;
            if (v) v = (csm[bImgHWW + ys * 96 + xs] != 0.f);
            vmask |= (v ? 1u : 0u) << t;
        }
    } else {
        ryz = blockIdx.z >> 1; rxz = blockIdx.z & 1;
    }
    const u16* WbZ = Wb + (MODE == 2 ? (long)blockIdx.z * 32 * 256 : 0);
    int n0 = blockIdx.y * BN;

    auto loadTile = [&](int kt, uint4& va0, uint4& va1) {
        va0 = make_uint4(0u, 0u, 0u, 0u); va1 = make_uint4(0u, 0u, 0u, 0u);
        if (MODE == 0) {
            constexpr int KTC = ICP / 32;
            int t = kt / KTC;
            int c0 = (kt - t * KTC) << 5;
            int dy = t / KW - PH, dx = t - (t / KW) * KW - PW;
            int iy = y0 * STRIDE + dy, ix = x0 * STRIDE + dx;
            if (iy >= 0 && iy < IH && ix >= 0 && ix < IW) {
                const u16* sp = Arow + (long)(dy * IW + dx) * ICP + c0;
                va0 = *(const uint4*)sp; va1 = *(const uint4*)(sp + 8);
            }
        } else if (MODE == 1) {
            int t = kt >> 1, half = kt & 1;
            if ((vmask >> t) & 1u) {
                int dy = t / 3 - 1, dx = t % 3 - 1;
                int yy = y0 + dy, xx = x0 + dx;
                const u16* sp = half ? (A1 + (((long)bImgHWW + (yy + djS) * 96 + (xx + diS)) << 5) + khOff)
                                     : (A0 + (((long)bImgHWW + yy * 96 + xx) << 5) + khOff);
                va0 = *(const uint4*)sp; va1 = *(const uint4*)(sp + 8);
            }
        } else {
            int t = kt >> 1, c0 = (kt & 1) << 5;
            int ta = t >> 1, tb = t & 1;
            int iy = y0 + ryz + ta - 1, ix = x0 + rxz + tb - 1;
            if (iy >= 0 && iy < 32 && ix >= 0 && ix < 48) {
                const u16* sp = A0 + (((long)(nImg * 32 + iy) * 48 + ix) << 6) + c0 + khOff;
                va0 = *(const uint4*)sp; va1 = *(const uint4*)(sp + 8);
            }
        }
    };

    int lane = tid & 63, wid = tid >> 6;
    int wm = (BN == 128) ? (wid >> 1) : wid;
    int wn = (BN == 128) ? (wid & 1) : 0;
    int fr = lane & 15, fg = lane >> 4;
    f32x4 acc[MF][NF];
    #pragma unroll
    for (int i = 0; i < MF; ++i)
        #pragma unroll
        for (int j = 0; j < NF; ++j)
            acc[i][j] = (f32x4){0.f, 0.f, 0.f, 0.f};

    bool bldr = (tid < 2 * BN);
    int brow = tid >> 1, ko = (tid & 1) << 4;
    const u16* Bp = WbZ + (long)(n0 + brow) * (NKT * 32) + ko;

    // prologue: stage K-step 0 into buffer 0
    {
        uint4 a0c, a1c;
        loadTile(0, a0c, a1c);
        *(uint4*)&As[0][mrow * LDR + khOff] = a0c;
        *(uint4*)&As[0][mrow * LDR + khOff + 8] = a1c;
        if (bldr) {
            *(uint4*)&Bs[0][brow * LDR + ko] = *(const uint4*)Bp;
            *(uint4*)&Bs[0][brow * LDR + ko + 8] = *(const uint4*)(Bp + 8);
        }
    }
    __syncthreads();

    for (int kt = 0; kt < NKT; ++kt) {
        int cur = kt & 1;
        bool hasNext = (kt + 1 < NKT);
        uint4 na0, na1, nb0, nb1;
        if (hasNext) {
            loadTile(kt + 1, na0, na1);
            if (bldr) {
                const u16* wp = Bp + (long)(kt + 1) * 32;
                nb0 = *(const uint4*)wp; nb1 = *(const uint4*)(wp + 8);
            }
        }
        bf16x8 af[MF], bfv[NF];
        #pragma unroll
        for (int i = 0; i < MF; ++i)
            af[i] = *(const bf16x8*)&As[cur][(wm * WTM + i * 16 + fr) * LDR + fg * 8];
        #pragma unroll
        for (int j = 0; j < NF; ++j)
            bfv[j] = *(const bf16x8*)&Bs[cur][(wn * WTN + j * 16 + fr) * LDR + fg * 8];
        #pragma unroll
        for (int i = 0; i < MF; ++i)
            #pragma unroll
            for (int j = 0; j < NF; ++j)
                acc[i][j] = __builtin_amdgcn_mfma_f32_16x16x32_bf16(af[i], bfv[j], acc[i][j], 0, 0, 0);
        if (hasNext) {
            int bufn = cur ^ 1;
            *(uint4*)&As[bufn][mrow * LDR + khOff] = na0;
            *(uint4*)&As[bufn][mrow * LDR + khOff + 8] = na1;
            if (bldr) {
                *(uint4*)&Bs[bufn][brow * LDR + ko] = nb0;
                *(uint4*)&Bs[bufn][brow * LDR + ko + 8] = nb1;
            }
            __syncthreads();
        }
    }

    // epilogue
    #pragma unroll
    for (int i = 0; i < MF; ++i) {
        #pragma unroll
        for (int j = 0; j < NF; ++j) {
            int nn = n0 + wn * WTN + j * 16 + fr;
            if (nn >= OC) continue;
            #pragma unroll
            for (int rr = 0; rr < 4; ++rr) {
                int mloc = wm * WTM + i * 16 + fg * 4 + rr;
                long gm = (long)blockIdx.x * 128 + mloc;
                float v = acc[i][j][rr] + bias[nn];
                if (ACT == 1) v = fmaxf(v, 0.f);
                else if (ACT == 2) v = lrelu_(v);
                if (OUTF32) {
                    outf[gm * ldc + coff + nn] = v;
                } else if (MODE == 2) {
                    int nI = (int)(gm / 1536); int rq = (int)(gm - (long)nI * 1536);
                    int Y = rq / 48, X = rq - (rq / 48) * 48;
                    long di = (((long)nI * 64 + 2 * Y + ryz) * 96 + (2 * X + rxz)) * 32 + nn;
                    outb[di] = f2bf(v);
                } else {
                    long di = gm * ldc + coff + nn;
                    u16 hv = f2bf(v);
                    outb[di] = hv;
                    if (outb2) outb2[di] = hv;
                }
            }
        }
    }
}

// ======== conv5 (32->1, 3x3) scalar over NHWC bf16 -> cvolT [b][p][64] bf16 ========
__global__ __launch_bounds__(256) void k_conv5n(const u16* __restrict__ x5, const float* __restrict__ w5t,
                                                const float* __restrict__ b5, u16* __restrict__ cvolT,
                                                int N, int n0)
{
    int idx = blockIdx.x * 256 + threadIdx.x;
    if (idx >= N * HWW) return;
    int nl = idx / HWW, p = idx % HWW, y = p / 96, x = p % 96;
    float acc = b5[0];
    #pragma unroll
    for (int t = 0; t < 9; ++t) {
        int iy = y + t / 3 - 1, ix = x + t % 3 - 1;
        if (iy < 0 || iy >= 64 || ix < 0 || ix >= 96) continue;
        const u16* sp = x5 + (((long)nl * HWW + iy * 96 + ix) << 5);
        const float* wt_ = w5t + t * 32;
        #pragma unroll
        for (int c8 = 0; c8 < 4; ++c8) {
            uint4 v = *(const uint4*)(sp + c8 * 8);
            acc = fmaf(bf2f((u16)(v.x & 0xffffu)), wt_[c8 * 8 + 0], acc);
            acc = fmaf(bf2f((u16)(v.x >> 16)),     wt_[c8 * 8 + 1], acc);
            acc = fmaf(bf2f((u16)(v.y & 0xffffu)), wt_[c8 * 8 + 2], acc);
            acc = fmaf(bf2f((u16)(v.y >> 16)),     wt_[c8 * 8 + 3], acc);
            acc = fmaf(bf2f((u16)(v.z & 0xffffu)), wt_[c8 * 8 + 4], acc);
            acc = fmaf(bf2f((u16)(v.z >> 16)),     wt_[c8 * 8 + 5], acc);
            acc = fmaf(bf2f((u16)(v.w & 0xffffu)), wt_[c8 * 8 + 6], acc);
            acc = fmaf(bf2f((u16)(v.w >> 16)),     wt_[c8 * 8 + 7], acc);
        }
    }
    int n = n0 + nl;
    int b = n / 49, k = n - b * 49;
    cvolT[((long)b * HWW + p) * 64 + k] = f2bf(acc);
}

// ======== mein ch 49..95 (fmap1, flow, zero-pad); 6-way channel split ========
__global__ __launch_bounds__(256) void k_me_tail(const float* __restrict__ fmap1, const float* __restrict__ flow,
                                                 u16* __restrict__ mein)
{
    int gid = blockIdx.x * 256 + threadIdx.x;
    if (gid >= 73728) return;
    int j = gid / 12288, idx = gid - j * 12288;
    int b = idx / HWW, p = idx % HWW;
    int c0 = 49 + j * 8;
    u16* mp = mein + (long)idx * 96;
    #pragma unroll
    for (int q = 0; q < 8; ++q) {
        int c = c0 + q;
        if (c >= 96) break;
        float v;
        if (c < 81) v = fmap1[((long)(b * 32 + (c - 49))) * HWW + p];
        else if (c == 81) v = flow[(b * 2 + 0) * HWW + p];
        else if (c == 82) v = flow[(b * 2 + 1) * HWW + p];
        else v = 0.f;
        mp[c] = f2bf(v);
    }
}

// ======== set hx head from h (NCHW f32) + hst + flow tails; 4-way channel split ========
__global__ __launch_bounds__(256) void k_set_head(const float* __restrict__ h, const float* __restrict__ flow,
                                                  float* __restrict__ hst, u16* __restrict__ hx,
                                                  u16* __restrict__ hx2)
{
    int gid = blockIdx.x * 256 + threadIdx.x;
    if (gid >= 49152) return;
    int cq = gid / 12288, idx = gid - cq * 12288;
    int b = idx / HWW, p = idx % HWW;
    int c0 = cq * 32;
    const float* hp = h + (long)b * 128 * HWW + p;
    float* hs = hst + (long)idx * 128;
    u16* hxp = hx + (long)idx * 224;
    #pragma unroll
    for (int c = c0; c < c0 + 32; c += 8) {
        float v[8];
        #pragma unroll
        for (int q = 0; q < 8; ++q) v[q] = hp[(long)(c + q) * HWW];
        *(float4*)&hs[c] = make_float4(v[0], v[1], v[2], v[3]);
        *(float4*)&hs[c + 4] = make_float4(v[4], v[5], v[6], v[7]);
        uint4 pk = make_uint4(pk2(v[0], v[1]), pk2(v[2], v[3]), pk2(v[4], v[5]), pk2(v[6], v[7]));
        *(uint4*)&hxp[c] = pk;
    }
    if (cq == 0) {
        u16 uu = f2bf(flow[(b * 2 + 0) * HWW + p]);
        u16 vv = f2bf(flow[(b * 2 + 1) * HWW + p]);
        long o = (long)idx * 224;
        hx[o + 222] = uu; hx[o + 223] = vv;
        hx2[o + 222] = uu; hx2[o + 223] = vv;
    }
}

// ======== GRU post z/r; 4-way channel split ========
__global__ __launch_bounds__(256) void k_post_zr(const float* __restrict__ azr, const float* __restrict__ hst,
                                                 float* __restrict__ z, u16* __restrict__ hx2)
{
    int gid = blockIdx.x * 256 + threadIdx.x;
    if (gid >= 49152) return;
    int cq = gid / 12288, idx = gid - cq * 12288;
    int c0 = cq * 32;
    const float* ap = azr + (long)idx * 256;
    const float* hs = hst + (long)idx * 128;
    float* zp = z + (long)idx * 128;
    u16* xp = hx2 + (long)idx * 224;
    #pragma unroll
    for (int c = c0; c < c0 + 32; c += 8) {
        float4 a0 = *(const float4*)&ap[c], a1 = *(const float4*)&ap[c + 4];
        float4 r0 = *(const float4*)&ap[128 + c], r1 = *(const float4*)&ap[128 + c + 4];
        float4 h0 = *(const float4*)&hs[c], h1v = *(const float4*)&hs[c + 4];
        float z0 = sigmoidf_(a0.x), z1 = sigmoidf_(a0.y), z2 = sigmoidf_(a0.z), z3 = sigmoidf_(a0.w);
        float z4 = sigmoidf_(a1.x), z5 = sigmoidf_(a1.y), z6 = sigmoidf_(a1.z), z7 = sigmoidf_(a1.w);
        *(float4*)&zp[c] = make_float4(z0, z1, z2, z3);
        *(float4*)&zp[c + 4] = make_float4(z4, z5, z6, z7);
        float rh0 = sigmoidf_(r0.x) * h0.x, rh1 = sigmoidf_(r0.y) * h0.y;
        float rh2 = sigmoidf_(r0.z) * h0.z, rh3 = sigmoidf_(r0.w) * h0.w;
        float rh4 = sigmoidf_(r1.x) * h1v.x, rh5 = sigmoidf_(r1.y) * h1v.y;
        float rh6 = sigmoidf_(r1.z) * h1v.z, rh7 = sigmoidf_(r1.w) * h1v.w;
        uint4 pk = make_uint4(pk2(rh0, rh1), pk2(rh2, rh3), pk2(rh4, rh5), pk2(rh6, rh7));
        *(uint4*)&xp[c] = pk;
    }
}

// ======== GRU post q; 4-way channel split ========
template<int FIN>
__global__ __launch_bounds__(256) void k_post_q(const float* __restrict__ aq, const float* __restrict__ z,
                                                const float* __restrict__ hst, float* __restrict__ h1f,
                                                u16* __restrict__ hxdst, float* __restrict__ outH)
{
    int gid = blockIdx.x * 256 + threadIdx.x;
    if (gid >= 49152) return;
    int cq = gid / 12288, idx = gid - cq * 12288;
    int b = idx / HWW, p = idx % HWW;
    int c0 = cq * 32;
    const float* ap = aq + (long)idx * 128;
    const float* zp = z + (long)idx * 128;
    const float* hs = hst + (long)idx * 128;
    #pragma unroll
    for (int c = c0; c < c0 + 32; c += 8) {
        float hn[8];
        #pragma unroll
        for (int q = 0; q < 8; ++q) {
            float qq = tanhf(ap[c + q]);
            float zv = zp[c + q];
            hn[q] = (1.f - zv) * hs[c + q] + zv * qq;
        }
        uint4 pk = make_uint4(pk2(hn[0], hn[1]), pk2(hn[2], hn[3]), pk2(hn[4], hn[5]), pk2(hn[6], hn[7]));
        if (FIN == 0) {
            *(float4*)&h1f[(long)idx * 128 + c] = make_float4(hn[0], hn[1], hn[2], hn[3]);
            *(float4*)&h1f[(long)idx * 128 + c + 4] = make_float4(hn[4], hn[5], hn[6], hn[7]);
            *(uint4*)&hxdst[(long)idx * 224 + c] = pk;
        } else {
            #pragma unroll
            for (int q = 0; q < 8; ++q)
                outH[((long)(b * 128 + c + q)) * HWW + p] = hn[q];
            *(uint4*)&hxdst[(long)idx * 128 + c] = pk;
        }
    }
}

// ======== softmax + expectation + flow add ========
__global__ __launch_bounds__(256) void k_soft(const float* __restrict__ s2, const float* __restrict__ flow,
                                              float* __restrict__ outFlow)
{
    int idx = blockIdx.x * 256 + threadIdx.x;
    if (idx >= 12288) return;
    int b = idx / HWW, p = idx % HWW;
    const float* sp = s2 + (long)idx * 64;
    float lg[49];
    #pragma unroll
    for (int k = 0; k < 48; k += 4) {
        float4 v = *(const float4*)&sp[k];
        lg[k] = v.x; lg[k + 1] = v.y; lg[k + 2] = v.z; lg[k + 3] = v.w;
    }
    lg[48] = sp[48];
    float m = -1e30f;
    #pragma unroll
    for (int k = 0; k < 49; ++k) m = fmaxf(m, lg[k]);
    float s = 0.f, a0 = 0.f, a1 = 0.f;
    #pragma unroll
    for (int k = 0; k < 49; ++k) {
        float e = expf(lg[k] - m);
        s += e;
        a0 += e * (float)(k / 7 - 3);
        a1 += e * (float)(k % 7 - 3);
    }
    float inv = 1.f / s;
    outFlow[(long)(b * 2 + 0) * HWW + p] = flow[(long)(b * 2 + 0) * HWW + p] + a0 * inv;
    outFlow[(long)(b * 2 + 1) * HWW + p] = flow[(long)(b * 2 + 1) * HWW + p] + a1 * inv;
}

extern "C" void kernel_launch(void* const* d_in, const int* in_sizes, int n_in,
                              void* d_out, int out_size, void* d_ws, size_t ws_size,
                              hipStream_t stream)
{
    const float* fmap1 = (const float*)d_in[0];
    const float* fmap2 = (const float*)d_in[1];
    const float* h     = (const float*)d_in[2];
    const float* flow  = (const float*)d_in[3];
    int pb = (in_sizes[4] == 1) ? 5 : 4;
    const float* mn_w1 = (const float*)d_in[pb + 0];
    const float* mn_b1 = (const float*)d_in[pb + 1];
    const float* mn_w2 = (const float*)d_in[pb + 2];
    const float* mn_b2 = (const float*)d_in[pb + 3];
    const float* mn_w3 = (const float*)d_in[pb + 4];
    const float* mn_b3 = (const float*)d_in[pb + 5];
    const float* mn_w4 = (const float*)d_in[pb + 6];
    const float* mn_b4 = (const float*)d_in[pb + 7];
    const float* mn_wd = (const float*)d_in[pb + 8];
    const float* mn_bd = (const float*)d_in[pb + 9];
    const float* mn_w5 = (const float*)d_in[pb + 10];
    const float* mn_b5 = (const float*)d_in[pb + 11];
    const float* dap_w = (const float*)d_in[pb + 12];
    const float* dap_b = (const float*)d_in[pb + 13];
    const float* me_w1 = (const float*)d_in[pb + 14];
    const float* me_b1 = (const float*)d_in[pb + 15];
    const float* me_w2 = (const float*)d_in[pb + 16];
    const float* me_b2 = (const float*)d_in[pb + 17];
    const float* me_w3 = (const float*)d_in[pb + 18];
    const float* me_b3 = (const float*)d_in[pb + 19];
    const float* gz1_w = (const float*)d_in[pb + 20];
    const float* gz1_b = (const float*)d_in[pb + 21];
    const float* gr1_w = (const float*)d_in[pb + 22];
    const float* gr1_b = (const float*)d_in[pb + 23];
    const float* gq1_w = (const float*)d_in[pb + 24];
    const float* gq1_b = (const float*)d_in[pb + 25];
    const float* gz2_w = (const float*)d_in[pb + 26];
    const float* gz2_b = (const float*)d_in[pb + 27];
    const float* gr2_w = (const float*)d_in[pb + 28];
    const float* gr2_b = (const float*)d_in[pb + 29];
    const float* gq2_w = (const float*)d_in[pb + 30];
    const float* gq2_b = (const float*)d_in[pb + 31];
    const float* fh_w1 = (const float*)d_in[pb + 32];
    const float* fh_b1 = (const float*)d_in[pb + 33];
    const float* fh_w2 = (const float*)d_in[pb + 34];
    const float* fh_b2 = (const float*)d_in[pb + 35];

    char* wsB = (char*)d_ws;
    size_t off = 0;
    auto alc = [&](size_t bytes) { size_t o = off; off = (off + bytes + 255) & ~(size_t)255; return o; };

    // ---- weight arena (memset to 0 first) ----
    size_t o_wc1  = alc(128 * 576 * 2);
    size_t o_wc2  = alc(128 * 864 * 2);
    size_t o_wc3  = alc((size_t)128 * 1152 * 2);
    size_t o_wc4  = alc((size_t)64 * 1152 * 2);
    size_t o_wdq  = alc(32768 * 2);
    size_t o_wme1 = alc(128 * 864 * 2);
    size_t o_wme2 = alc((size_t)128 * 1152 * 2);
    size_t o_wme3 = alc((size_t)128 * 1152 * 2);
    size_t o_wzr1 = alc((size_t)256 * 1120 * 2);
    size_t o_wq1  = alc((size_t)128 * 1120 * 2);
    size_t o_wzr2 = alc((size_t)256 * 1120 * 2);
    size_t o_wq2  = alc((size_t)128 * 1120 * 2);
    size_t o_wfh1 = alc(256 * 128 * 2);
    size_t o_wfh2 = alc(64 * 256 * 2);
    size_t o_wdapb= alc(64 * 64 * 2);
    size_t o_w5t  = alc(288 * 4);
    size_t o_bzr1 = alc(256 * 4);
    size_t o_bzr2 = alc(256 * 4);
    size_t wArenaBytes = off;

    // ---- persistent activations ----
    size_t o_f1bf = alc((size_t)12288 * 32 * 2);
    size_t o_f2wb = alc((size_t)12288 * 32 * 2);
    size_t o_cs   = alc(12288 * 4);
    size_t o_cvolT= alc((size_t)12288 * 64 * 2);

    // ---- shared region: phase-A x-scratch (CH=49) overlaid with phase-B buffers ----
    const int CH = 49;
    size_t sharedBase = off;
    size_t offA = sharedBase;
    auto alcA = [&](size_t bytes) { size_t o = offA; offA = (offA + bytes + 255) & ~(size_t)255; return o; };
    size_t o_x1 = alcA((size_t)CH * 6144 * 96 * 2);
    size_t o_x2 = alcA((size_t)CH * 1536 * 128 * 2);
    size_t o_x3 = alcA((size_t)CH * 1536 * 128 * 2);
    size_t o_x4 = alcA((size_t)CH * 1536 * 64 * 2);
    size_t o_x5 = alcA((size_t)CH * 6144 * 32 * 2);
    size_t offB2 = sharedBase;
    auto alcB = [&](size_t bytes) { size_t o = offB2; offB2 = (offB2 + bytes + 255) & ~(size_t)255; return o; };
    size_t o_mein = alcB((size_t)12288 * 96 * 2);
    size_t o_m1   = alcB((size_t)12288 * 128 * 2);
    size_t o_m2   = alcB((size_t)12288 * 128 * 2);
    size_t o_hx   = alcB((size_t)12288 * 224 * 2);
    size_t o_hx2  = alcB((size_t)12288 * 224 * 2);
    size_t o_h2bf = alcB((size_t)12288 * 128 * 2);
    size_t o_s1b  = alcB((size_t)12288 * 256 * 2);
    size_t o_hst  = alcB((size_t)12288 * 128 * 4);
    size_t o_h1f  = alcB((size_t)12288 * 128 * 4);
    size_t o_zf   = alcB((size_t)12288 * 128 * 4);
    size_t o_azr  = alcB((size_t)12288 * 256 * 4);
    size_t o_aqf  = alcB((size_t)12288 * 128 * 4);
    size_t o_s2   = alcB((size_t)12288 * 64 * 4);

    u16* wbase = (u16*)wsB;
    u16* wdq  = (u16*)(wsB + o_wdq);
    float* w5t = (float*)(wsB + o_w5t);
    float* bzr1 = (float*)(wsB + o_bzr1);
    float* bzr2 = (float*)(wsB + o_bzr2);
    u16* wc1  = (u16*)(wsB + o_wc1);   u16* wc2  = (u16*)(wsB + o_wc2);
    u16* wc3  = (u16*)(wsB + o_wc3);   u16* wc4  = (u16*)(wsB + o_wc4);
    u16* wme1 = (u16*)(wsB + o_wme1);  u16* wme2 = (u16*)(wsB + o_wme2);
    u16* wme3 = (u16*)(wsB + o_wme3);
    u16* wzr1 = (u16*)(wsB + o_wzr1);  u16* wq1  = (u16*)(wsB + o_wq1);
    u16* wzr2 = (u16*)(wsB + o_wzr2);  u16* wq2  = (u16*)(wsB + o_wq2);
    u16* wfh1 = (u16*)(wsB + o_wfh1);  u16* wfh2 = (u16*)(wsB + o_wfh2);
    u16* wdapb= (u16*)(wsB + o_wdapb);

    u16* f1bf = (u16*)(wsB + o_f1bf);  u16* f2wb = (u16*)(wsB + o_f2wb);
    float* cs = (float*)(wsB + o_cs);
    u16* cvolT = (u16*)(wsB + o_cvolT);
    u16* x1 = (u16*)(wsB + o_x1); u16* x2 = (u16*)(wsB + o_x2); u16* x3 = (u16*)(wsB + o_x3);
    u16* x4 = (u16*)(wsB + o_x4); u16* x5 = (u16*)(wsB + o_x5);
    u16* mein = (u16*)(wsB + o_mein);
    u16* m1 = (u16*)(wsB + o_m1); u16* m2 = (u16*)(wsB + o_m2);
    u16* hx = (u16*)(wsB + o_hx); u16* hx2 = (u16*)(wsB + o_hx2);
    u16* h2bf = (u16*)(wsB + o_h2bf);  u16* s1b = (u16*)(wsB + o_s1b);
    float* hst = (float*)(wsB + o_hst); float* h1f = (float*)(wsB + o_h1f);
    float* zf = (float*)(wsB + o_zf); float* azr = (float*)(wsB + o_azr);
    float* aqf = (float*)(wsB + o_aqf); float* s2 = (float*)(wsB + o_s2);

    float* outH = (float*)d_out;
    float* outFlow = outH + (long)2 * 128 * HWW;

    auto nb = [](long total, int bs) { return (unsigned)((total + bs - 1) / bs); };

    // ---- weight preps ----
    hipMemsetAsync(wsB, 0, wArenaBytes, stream);
    hipMemsetAsync(wsB + o_cvolT, 0, (size_t)12288 * 64 * 2, stream);

    WJobs J;
    {
        auto mk = [](const float* src, size_t dstOffBytes, int OC, int rowOff, int IC, int ICP, int NT) {
            WJob w; w.src = src; w.dstOff = dstOffBytes / 2; w.OC = OC; w.rowOff = rowOff;
            w.IC = IC; w.ICP = ICP; w.NT = NT; w.cum = 0; return w;
        };
        J.j[0]  = mk(mn_w1, o_wc1, 96, 0, 64, 64, 9);
        J.j[1]  = mk(mn_w2, o_wc2, 128, 0, 96, 96, 9);
        J.j[2]  = mk(mn_w3, o_wc3, 128, 0, 128, 128, 9);
        J.j[3]  = mk(mn_w4, o_wc4, 64, 0, 128, 128, 9);
        J.j[4]  = mk(me_w1, o_wme1, 128, 0, 83, 96, 9);
        J.j[5]  = mk(me_w2, o_wme2, 128, 0, 128, 128, 9);
        J.j[6]  = mk(me_w3, o_wme3, 94, 0, 128, 128, 9);
        J.j[7]  = mk(gz1_w, o_wzr1, 128, 0, 224, 224, 5);
        J.j[8]  = mk(gr1_w, o_wzr1, 128, 128, 224, 224, 5);
        J.j[9]  = mk(gq1_w, o_wq1, 128, 0, 224, 224, 5);
        J.j[10] = mk(gz2_w, o_wzr2, 128, 0, 224, 224, 5);
        J.j[11] = mk(gr2_w, o_wzr2, 128, 128, 224, 224, 5);
        J.j[12] = mk(gq2_w, o_wq2, 128, 0, 224, 224, 5);
        J.j[13] = mk(fh_w1, o_wfh1, 256, 0, 128, 128, 1);
        J.j[14] = mk(fh_w2, o_wfh2, 49, 0, 256, 256, 1);
        J.j[15] = mk(dap_w, o_wdapb, 49, 0, 49, 64, 1);
        long cum = 0;
        for (int k = 0; k < 16; ++k) {
            J.j[k].cum = cum;
            cum += (long)J.j[k].OC * J.j[k].NT * J.j[k].ICP;
        }
        J.total = cum;
    }
    k_wt_all<<<nb(J.total, 256), 256, 0, stream>>>(J, wbase);
    k_wt_dq<<<nb(32768, 256), 256, 0, stream>>>(mn_wd, wdq);
    k_wt5<<<2, 256, 0, stream>>>(mn_w5, w5t);
    k_catb<<<1, 256, 0, stream>>>(gz1_b, gr1_b, bzr1);
    k_catb<<<1, 256, 0, stream>>>(gz2_b, gr2_b, bzr2);

    // ---- input preps ----
    k_prep_f1<<<nb(24576, 256), 256, 0, stream>>>(fmap1, f1bf);
    k_warp<<<nb(24576, 256), 256, 0, stream>>>(fmap2, flow, f2wb, cs);

    // ---- matching net: 2 chunks of 49 displacement-batches ----
    for (int n0 = 0; n0 < 98; n0 += CH) {
        k_gemm<128,1,3,3,1,1,1,1,0,64,96,64,96,32,18><<<dim3(2352, 1), 256, 0, stream>>>(
            f1bf, f2wb, cs, wc1, mn_b1, x1, nullptr, nullptr, 96, 96, 0, n0);
        k_gemm<128,0,3,3,1,1,2,1,0,64,96,32,48,96,27><<<dim3(588, 1), 256, 0, stream>>>(
            x1, nullptr, nullptr, wc2, mn_b2, x2, nullptr, nullptr, 128, 128, 0, 0);
        k_gemm<128,0,3,3,1,1,1,1,0,32,48,32,48,128,36><<<dim3(588, 1), 256, 0, stream>>>(
            x2, nullptr, nullptr, wc3, mn_b3, x3, nullptr, nullptr, 128, 128, 0, 0);
        k_gemm<64,0,3,3,1,1,1,1,0,32,48,32,48,128,36><<<dim3(588, 1), 256, 0, stream>>>(
            x3, nullptr, nullptr, wc4, mn_b4, x4, nullptr, nullptr, 64, 64, 0, 0);
        k_gemm<32,2,4,4,2,2,1,1,0,32,48,32,48,64,8><<<dim3(588, 1, 4), 256, 0, stream>>>(
            x4, nullptr, nullptr, wdq, mn_bd, x5, nullptr, nullptr, 32, 32, 0, 0);
        k_conv5n<<<nb((long)CH * HWW, 256), 256, 0, stream>>>(x5, w5t, mn_b5, cvolT, CH, n0);
    }

    // ---- DAP (MFMA GEMM) + me tail ----
    k_gemm<64,0,1,1,0,0,1,0,0,64,96,64,96,64,2><<<dim3(96, 1), 256, 0, stream>>>(
        cvolT, nullptr, nullptr, wdapb, dap_b, mein, nullptr, nullptr, 49, 96, 0, 0);
    k_me_tail<<<nb(73728, 256), 256, 0, stream>>>(fmap1, flow, mein);

    // ---- motion encoder ----
    k_gemm<128,0,3,3,1,1,1,2,0,64,96,64,96,96,27><<<dim3(96, 1), 256, 0, stream>>>(
        mein, nullptr, nullptr, wme1, me_b1, m1, nullptr, nullptr, 128, 128, 0, 0);
    k_gemm<128,0,3,3,1,1,1,2,0,64,96,64,96,128,36><<<dim3(96, 1), 256, 0, stream>>>(
        m1, nullptr, nullptr, wme2, me_b2, m2, nullptr, nullptr, 128, 128, 0, 0);
    k_gemm<128,0,3,3,1,1,1,0,0,64,96,64,96,128,36><<<dim3(96, 1), 256, 0, stream>>>(
        m2, nullptr, nullptr, wme3, me_b3, hx, hx2, nullptr, 94, 224, 128, 0);

    // ---- GRU 1 (horizontal 1x5) ----
    k_set_head<<<nb(49152, 256), 256, 0, stream>>>(h, flow, hst, hx, hx2);
    k_gemm<128,0,1,5,0,2,1,0,1,64,96,64,96,224,35><<<dim3(96, 2), 256, 0, stream>>>(
        hx, nullptr, nullptr, wzr1, bzr1, nullptr, nullptr, azr, 256, 256, 0, 0);
    k_post_zr<<<nb(49152, 256), 256, 0, stream>>>(azr, hst, zf, hx2);
    k_gemm<128,0,1,5,0,2,1,0,1,64,96,64,96,224,35><<<dim3(96, 1), 256, 0, stream>>>(
        hx2, nullptr, nullptr, wq1, gq1_b, nullptr, nullptr, aqf, 128, 128, 0, 0);
    k_post_q<0><<<nb(49152, 256), 256, 0, stream>>>(aqf, zf, hst, h1f, hx, nullptr);

    // ---- GRU 2 (vertical 5x1) ----
    k_gemm<128,0,5,1,2,0,1,0,1,64,96,64,96,224,35><<<dim3(96, 2), 256, 0, stream>>>(
        hx, nullptr, nullptr, wzr2, bzr2, nullptr, nullptr, azr, 256, 256, 0, 0);
    k_post_zr<<<nb(49152, 256), 256, 0, stream>>>(azr, h1f, zf, hx2);
    k_gemm<128,0,5,1,2,0,1,0,1,64,96,64,96,224,35><<<dim3(96, 1), 256, 0, stream>>>(
        hx2, nullptr, nullptr, wq2, gq2_b, nullptr, nullptr, aqf, 128, 128, 0, 0);
    k_post_q<1><<<nb(49152, 256), 256, 0, stream>>>(aqf, zf, h1f, nullptr, h2bf, outH);

    // ---- flow head ----
    k_gemm<128,0,1,1,0,0,1,2,0,64,96,64,96,128,4><<<dim3(96, 2), 256, 0, stream>>>(
        h2bf, nullptr, nullptr, wfh1, fh_b1, s1b, nullptr, nullptr, 256, 256, 0, 0);
    k_gemm<64,0,1,1,0,0,1,2,1,64,96,64,96,256,8><<<dim3(96, 1), 256, 0, stream>>>(
        s1b, nullptr, nullptr, wfh2, fh_b2, nullptr, nullptr, s2, 49, 64, 0, 0);
    k_soft<<<nb(12288, 256), 256, 0, stream>>>(s2, flow, outFlow);
}